// Round 3
// baseline (1534.588 us; speedup 1.0000x reference)
//
#include <hip/hip_runtime.h>
#include <hip/hip_bf16.h>
#include <math.h>

typedef __hip_bfloat16 bf16;
typedef __attribute__((ext_vector_type(8))) short s8v;
typedef __attribute__((ext_vector_type(4))) float f4v;

__device__ __forceinline__ float ldf(const float* p) { return *p; }
__device__ __forceinline__ float ldf(const bf16* p) { return __bfloat162float(*p); }
__device__ __forceinline__ void stf(float* p, float v) { *p = v; }
__device__ __forceinline__ void stf(bf16* p, float v) { *p = __float2bfloat16(v); }

__device__ __forceinline__ float gelu_tanh(float x) {
    float x3 = x * x * x;
    return 0.5f * x * (1.f + tanhf(0.7978845608028654f * (x + 0.044715f * x3)));
}
__device__ __forceinline__ unsigned short bfbits(float x) {
    bf16 t = __float2bfloat16(x);
    return *(unsigned short*)&t;
}

// async global->LDS 16B: LDS dest must be wave-uniform base (+ lane*16 by HW);
// global src is per-lane.
__device__ __forceinline__ void gload16(const bf16* g, bf16* l)
{
    __builtin_amdgcn_global_load_lds(
        (const __attribute__((address_space(1))) unsigned int*)g,
        (__attribute__((address_space(3))) unsigned int*)l,
        16, 0, 0);
}

// ---------------- zero fill (16B granules) ----------------
__global__ __launch_bounds__(256) void fill0_k(uint4* __restrict__ p, int n16)
{
    int i = blockIdx.x * 256 + threadIdx.x;
    if (i < n16) p[i] = uint4{0u, 0u, 0u, 0u};
}

// ---------------- weight reorder: fp32 [OC][IC][T] -> bf16 [T][OC][IC] ----------------
__global__ __launch_bounds__(256) void wprep_k(const float* __restrict__ w, bf16* __restrict__ wr,
                                               int OC, int IC, int T)
{
    int i = blockIdx.x * 256 + threadIdx.x;
    if (i >= OC * IC * T) return;
    int t = i % T; int rem = i / T; int ic = rem % IC; int oc = rem / IC;
    wr[((size_t)t * OC + oc) * IC + ic] = __float2bfloat16(w[i]);
}

// ---------------- conv#1 weight prep: fp32 [OC][nic][ntap] -> bf16 [OC][Kp], k=tap*nic+ic ----------------
__global__ __launch_bounds__(256) void w1prep_k(const float* __restrict__ w, bf16* __restrict__ o,
                                                int OC, int nic, int ntap, int Kp)
{
    int i = blockIdx.x * 256 + threadIdx.x;
    if (i >= OC * Kp) return;
    int oc = i / Kp, k = i - oc * Kp;
    float v = 0.f;
    if (k < nic * ntap) {
        int tap = k / nic, ic = k - tap * nic;
        v = w[((size_t)oc * nic + ic) * ntap + tap];
    }
    o[i] = __float2bfloat16(v);
}

// ---------------- transpose cast: fp32 [K][N] -> bf16 [N][K] ----------------
__global__ __launch_bounds__(256) void tprep_k(const float* __restrict__ w, bf16* __restrict__ wt,
                                               int K, int N)
{
    int i = blockIdx.x * 256 + threadIdx.x;
    if (i >= K * N) return;
    int n = i % N, k = i / N;
    wt[(size_t)n * K + k] = __float2bfloat16(w[i]);
}

// ---------------- plain cast fp32 -> bf16 ----------------
__global__ __launch_bounds__(256) void cast_k(const float* __restrict__ w, bf16* __restrict__ o, int n)
{
    int i = blockIdx.x * 256 + threadIdx.x;
    if (i < n) o[i] = __float2bfloat16(w[i]);
}

// ---------------- im2col for conv3d#1: x3d fp32 [5][24][256][512] -> A bf16 [196608][160] ----------------
__global__ __launch_bounds__(256) void im2col3d_k(const float* __restrict__ x, bf16* __restrict__ A, int od0)
{
    int gid = blockIdx.x * 256 + threadIdx.x;  // 196608*20
    int m = gid / 20, kg = gid - 20 * (gid / 20);
    int ow = m & 255, rowid = m >> 8;
    int oh = rowid & 127, od = od0 + (rowid >> 7);
    int iz0 = 2 * od - 1, iy0 = 2 * oh - 1, ix0 = 2 * ow - 1;
    union { uint4 u; unsigned short h[8]; } pk;
#pragma unroll
    for (int j = 0; j < 8; j++) {
        int k = kg * 8 + j;
        float v = 0.f;
        if (k < 135) {
            int tap = k / 5, ic = k - tap * 5;
            int kz = tap / 9, r = tap - kz * 9;
            int ky = r / 3, kx = r - ky * 3;
            int iz = iz0 + kz, iy = iy0 + ky, ix = ix0 + kx;
            if ((unsigned)iz < 24u && (unsigned)iy < 256u && (unsigned)ix < 512u)
                v = x[(((size_t)ic * 24 + iz) * 256 + iy) * 512 + ix];
        }
        pk.h[j] = bfbits(v);
    }
    *(uint4*)&A[(size_t)m * 160 + kg * 8] = pk.u;
}

// ---------------- im2col for conv2d#1: x2d fp32 [8][256][512] -> A bf16 [32768][96] ----------------
__global__ __launch_bounds__(256) void im2col2d_k(const float* __restrict__ x, bf16* __restrict__ A)
{
    int gid = blockIdx.x * 256 + threadIdx.x;  // 32768*12
    int m = gid / 12, kg = gid - 12 * (gid / 12);
    int ow = m & 255, oh = m >> 8;
    int iy0 = 2 * oh - 1, ix0 = 2 * ow - 1;
    union { uint4 u; unsigned short h[8]; } pk;
#pragma unroll
    for (int j = 0; j < 8; j++) {
        int k = kg * 8 + j;
        float v = 0.f;
        if (k < 72) {
            int tap = k >> 3, ic = k & 7;
            int ky = tap / 3, kx = tap - ky * 3;
            int iy = iy0 + ky, ix = ix0 + kx;
            if ((unsigned)iy < 256u && (unsigned)ix < 512u)
                v = x[((size_t)ic * 256 + iy) * 512 + ix];
        }
        pk.h[j] = bfbits(v);
    }
    *(uint4*)&A[(size_t)m * 96 + kg * 8] = pk.u;
}

// ---------------- conv#1 GEMM: C = A[M][Kp] x W[128][Kp]^T, +bias, GELU, padded NHWC store ----------------
__global__ __launch_bounds__(256) void conv1_gemm(
    const bf16* __restrict__ A, const bf16* __restrict__ W, const float* __restrict__ bias,
    bf16* __restrict__ out, int M, int Kp, int rowOff)
{
    __shared__ __align__(16) bf16 As[128 * 32];
    __shared__ __align__(16) bf16 Bs[128 * 32];
    int tid = threadIdx.x;
    int m0 = blockIdx.x * 128;
    int wave = tid >> 6, lane = tid & 63;
    int wb = tid & 192;
    int wm = (wave >> 1) * 64, wn = (wave & 1) * 64;
    int lm = lane & 15, lq = lane >> 4;
    f4v acc[4][4];
#pragma unroll
    for (int i = 0; i < 4; i++)
#pragma unroll
        for (int j = 0; j < 4; j++) acc[i][j] = f4v{0.f, 0.f, 0.f, 0.f};
    for (int k0 = 0; k0 < Kp; k0 += 32) {
        __syncthreads();
#pragma unroll
        for (int c = 0; c < 2; c++) {
            int i = c * 256 + tid;
            int row = i >> 2, kq = i & 3;
            gload16(&A[(size_t)(m0 + row) * Kp + k0 + kq * 8], &As[(c * 256 + wb) * 8]);
            gload16(&W[(size_t)row * Kp + k0 + kq * 8], &Bs[(c * 256 + wb) * 8]);
        }
        __syncthreads();
        s8v af[4], bfr[4];
#pragma unroll
        for (int mi = 0; mi < 4; mi++) af[mi] = *(const s8v*)&As[(wm + mi * 16 + lm) * 32 + lq * 8];
#pragma unroll
        for (int ni = 0; ni < 4; ni++) bfr[ni] = *(const s8v*)&Bs[(wn + ni * 16 + lm) * 32 + lq * 8];
#pragma unroll
        for (int mi = 0; mi < 4; mi++)
#pragma unroll
            for (int ni = 0; ni < 4; ni++)
                acc[mi][ni] = __builtin_amdgcn_mfma_f32_16x16x32_bf16(af[mi], bfr[ni], acc[mi][ni], 0, 0, 0);
    }
#pragma unroll
    for (int mi = 0; mi < 4; mi++)
#pragma unroll
        for (int ni = 0; ni < 4; ni++)
#pragma unroll
            for (int r = 0; r < 4; r++) {
                int m = m0 + wm + mi * 16 + lq * 4 + r;
                int n = wn + ni * 16 + lm;
                int row = rowOff + (m >> 8), x = m & 255;
                float v = acc[mi][ni][r] + bias[n];
                out[((size_t)row * 258 + 1 + x) * 128 + n] = __float2bfloat16(gelu_tanh(v));
            }
}

// ================= MFMA tap-GEMM conv (#2/#3): 3 kx-taps per barrier =================
// 1D grid with XCD-aware swizzle.
template <int BM, int KD>
__global__ __launch_bounds__(256) void conv_mfma2(
    const bf16* __restrict__ in, const bf16* __restrict__ wr, const float* __restrict__ bias,
    bf16* __restrict__ out, int ID, int IH, int IWp, int IC,
    int OH, int OC, int OWS, int outPad, int nx)
{
    constexpr int NI = (BM == 128) ? 4 : 2;
    __shared__ __align__(16) bf16 As[3 * BM * 32];
    __shared__ __align__(16) bf16 Bs[3 * 128 * 32];
    int tid = threadIdx.x;
    int nwg = gridDim.x;                    // always a multiple of 8
    int bl = blockIdx.x;
    int swz = (bl & 7) * (nwg >> 3) + (bl >> 3);
    int n0 = (swz % nx) * 128;
    int rowid = swz / nx;
    int od = rowid / OH, oh = rowid % OH;
    int wave = tid >> 6, lane = tid & 63;
    int wb = tid & 192;                     // wave*64
    int wm = (BM == 128) ? (wave >> 1) * 64 : 0;
    int wn = (BM == 128) ? (wave & 1) * 64 : wave * 32;
    int lm = lane & 15, lq = lane >> 4;
    f4v acc[4][NI];
#pragma unroll
    for (int i = 0; i < 4; i++)
#pragma unroll
        for (int j = 0; j < NI; j++) acc[i][j] = f4v{0.f, 0.f, 0.f, 0.f};

    for (int kz = 0; kz < KD; kz++) {
        int iz = (KD == 3) ? (2 * od + kz - 1) : 0;
        if ((unsigned)iz >= (unsigned)ID) continue;
        for (int ky = 0; ky < 3; ky++) {
            int iy = 2 * oh + ky - 1;
            if ((unsigned)iy >= (unsigned)IH) continue;
            const bf16* inrow = in + ((size_t)iz * IH + iy) * IWp * IC;
            const bf16* wbase = wr + (size_t)((kz * 3 + ky) * 3) * OC * IC;
            for (int kb = 0; kb < IC; kb += 32) {
                __syncthreads();
#pragma unroll
                for (int c = 0; c < (3 * BM) / 64; c++) {
                    int i = c * 256 + tid;
                    int kx = i / (BM * 4);
                    int r = i - kx * (BM * 4);
                    int m = r >> 2, sub = r & 3;
                    gload16(&inrow[(size_t)(2 * m + kx) * IC + kb + sub * 8],
                            &As[(c * 256 + wb) * 8]);
                }
#pragma unroll
                for (int c = 0; c < 6; c++) {
                    int i = c * 256 + tid;
                    int t3 = i >> 9, r = i & 511, n = r >> 2, sub = r & 3;
                    gload16(&wbase[((size_t)t3 * OC + n0 + n) * IC + kb + sub * 8],
                            &Bs[(c * 256 + wb) * 8]);
                }
                __syncthreads();
#pragma unroll
                for (int kx = 0; kx < 3; kx++) {
                    s8v af[4], bfr[NI];
#pragma unroll
                    for (int mi = 0; mi < 4; mi++)
                        af[mi] = *(const s8v*)&As[(kx * BM + wm + mi * 16 + lm) * 32 + lq * 8];
#pragma unroll
                    for (int ni = 0; ni < NI; ni++)
                        bfr[ni] = *(const s8v*)&Bs[(kx * 128 + wn + ni * 16 + lm) * 32 + lq * 8];
#pragma unroll
                    for (int mi = 0; mi < 4; mi++)
#pragma unroll
                        for (int ni = 0; ni < NI; ni++)
                            acc[mi][ni] = __builtin_amdgcn_mfma_f32_16x16x32_bf16(af[mi], bfr[ni], acc[mi][ni], 0, 0, 0);
                }
            }
        }
    }
    size_t orowbase = ((size_t)rowid * OWS + outPad) * OC;
#pragma unroll
    for (int mi = 0; mi < 4; mi++)
#pragma unroll
        for (int ni = 0; ni < NI; ni++)
#pragma unroll
            for (int r = 0; r < 4; r++) {
                int m = wm + mi * 16 + lq * 4 + r;
                int n = n0 + wn + ni * 16 + lm;
                float v = acc[mi][ni][r] + bias[n];
                out[orowbase + (size_t)m * OC + n] = __float2bfloat16(gelu_tanh(v));
            }
}

// ================= MFMA GEMM: C[M,N] = A[M,K] * Bt[N,K]^T + bias (+res) (+vT side-write) ==========
template <typename OutT, int RES, int VT>
__global__ __launch_bounds__(256) void gemm_bt(
    const bf16* __restrict__ A, const bf16* __restrict__ Bt, const float* __restrict__ bias,
    OutT* __restrict__ C, const float* __restrict__ res, bf16* __restrict__ vt,
    int M, int N, int K)
{
    __shared__ __align__(16) bf16 As[128 * 32];
    __shared__ __align__(16) bf16 Bs[128 * 32];
    int tid = threadIdx.x;
    int n0 = blockIdx.x * 128, m0 = blockIdx.y * 128;
    int wave = tid >> 6, lane = tid & 63;
    int wb = tid & 192;
    int wm = (wave >> 1) * 64, wn = (wave & 1) * 64;
    int lm = lane & 15, lq = lane >> 4;
    f4v acc[4][4];
#pragma unroll
    for (int i = 0; i < 4; i++)
#pragma unroll
        for (int j = 0; j < 4; j++) acc[i][j] = f4v{0.f, 0.f, 0.f, 0.f};
    for (int k0 = 0; k0 < K; k0 += 32) {
        __syncthreads();
#pragma unroll
        for (int c = 0; c < 2; c++) {
            int i = c * 256 + tid;
            int row = i >> 2, kq = i & 3;
            gload16(&A[(size_t)(m0 + row) * K + k0 + kq * 8], &As[(c * 256 + wb) * 8]);
            gload16(&Bt[(size_t)(n0 + row) * K + k0 + kq * 8], &Bs[(c * 256 + wb) * 8]);
        }
        __syncthreads();
        s8v af[4], bfr[4];
#pragma unroll
        for (int mi = 0; mi < 4; mi++) af[mi] = *(const s8v*)&As[(wm + mi * 16 + lm) * 32 + lq * 8];
#pragma unroll
        for (int ni = 0; ni < 4; ni++) bfr[ni] = *(const s8v*)&Bs[(wn + ni * 16 + lm) * 32 + lq * 8];
#pragma unroll
        for (int mi = 0; mi < 4; mi++)
#pragma unroll
            for (int ni = 0; ni < 4; ni++)
                acc[mi][ni] = __builtin_amdgcn_mfma_f32_16x16x32_bf16(af[mi], bfr[ni], acc[mi][ni], 0, 0, 0);
    }
#pragma unroll
    for (int mi = 0; mi < 4; mi++)
#pragma unroll
        for (int ni = 0; ni < 4; ni++) {
            int n = n0 + wn + ni * 16 + lm;
            int mbase = m0 + wm + mi * 16 + lq * 4;
            float b = bias[n];
            if (VT && n >= 1024) {
                ushort4 pk;
                pk.x = bfbits(acc[mi][ni][0] + b);
                pk.y = bfbits(acc[mi][ni][1] + b);
                pk.z = bfbits(acc[mi][ni][2] + b);
                pk.w = bfbits(acc[mi][ni][3] + b);
                *(ushort4*)&vt[(size_t)(n - 1024) * 8192 + mbase] = pk;
            }
#pragma unroll
            for (int r = 0; r < 4; r++) {
                int m = mbase + r;
                float v = acc[mi][ni][r] + b;
                if (RES) v += res[(size_t)m * N + n];
                stf(&C[(size_t)m * N + n], v);
            }
        }
}

// ---------------- LayerNorm: lat fp32 [P,512] -> y bf16 [P,512]; one wave per token ----------------
__global__ __launch_bounds__(256) void ln_k(
    const float* __restrict__ lat, const float* __restrict__ g, const float* __restrict__ b,
    bf16* __restrict__ y)
{
    int tok = blockIdx.x * 4 + (threadIdx.x >> 6);
    int lane = threadIdx.x & 63;
    const float4* row = (const float4*)&lat[(size_t)tok * 512 + lane * 8];
    float4 a = row[0], c = row[1];
    float s = a.x + a.y + a.z + a.w + c.x + c.y + c.z + c.w;
    float ss = a.x * a.x + a.y * a.y + a.z * a.z + a.w * a.w
             + c.x * c.x + c.y * c.y + c.z * c.z + c.w * c.w;
#pragma unroll
    for (int off = 32; off; off >>= 1) {
        s += __shfl_xor(s, off);
        ss += __shfl_xor(ss, off);
    }
    float mu = s * (1.f / 512.f);
    float var = ss * (1.f / 512.f) - mu * mu;
    float rstd = rsqrtf(var + 1e-5f);
    const float4* gp = (const float4*)&g[lane * 8];
    const float4* bp = (const float4*)&b[lane * 8];
    float4 g0 = gp[0], g1 = gp[1], b0 = bp[0], b1 = bp[1];
    union { uint4 u; unsigned short h[8]; } pk;
    pk.h[0] = bfbits((a.x - mu) * rstd * g0.x + b0.x);
    pk.h[1] = bfbits((a.y - mu) * rstd * g0.y + b0.y);
    pk.h[2] = bfbits((a.z - mu) * rstd * g0.z + b0.z);
    pk.h[3] = bfbits((a.w - mu) * rstd * g0.w + b0.w);
    pk.h[4] = bfbits((c.x - mu) * rstd * g1.x + b1.x);
    pk.h[5] = bfbits((c.y - mu) * rstd * g1.y + b1.y);
    pk.h[6] = bfbits((c.z - mu) * rstd * g1.z + b1.z);
    pk.h[7] = bfbits((c.w - mu) * rstd * g1.w + b1.w);
    *(uint4*)&y[(size_t)tok * 512 + lane * 8] = pk.u;
}

// ================= MFMA flash-style neighborhood attention =================
// grid (128 rows, 8 heads); block 256 = 4 waves; wave handles (dz,dy) idx = wave + 4t.
// Band-aware softmax: x-band is 7 wide < 16 => each lane has at most ONE in-band
// column among its 4 ni candidates -> 1 select + 1 exp + 1 LDS write per (mi,r).
// P tile pre-zeroed once (zero pattern is offset-invariant). Defer-max branch skips
// the Oa rescale when no row's max grew (bitwise no-op). Heavy blocks scheduled first.
__global__ __launch_bounds__(256, 3) void natt_mfma(
    const bf16* __restrict__ qkv, const bf16* __restrict__ vT, bf16* __restrict__ o)
{
    __shared__ __align__(16) char smem[34816];
    bf16* qs = (bf16*)smem;                    // [64][80] bf16 (prologue only, aliases pb)
    float* obuf = (float*)smem;                // [64][65] fp32 (epilogue, aliases pb)
    float* mlb = (float*)(smem + 32768);       // [4 waves][2][64]
    int tid = threadIdx.x;
    // work-ordered remap: interior (heavy) blocks get low blockIdx -> start first,
    // light corner blocks form the drain tail.
    int bx = blockIdx.x;
    int rd = bx >> 5, rh = bx & 31;
    int d = (rd == 0) ? 1 : (rd == 1) ? 2 : (rd == 2) ? 0 : 3;
    int h = (rh < 26) ? (rh + 3) : (rh == 26) ? 2 : (rh == 27) ? 29
          : (rh == 28) ? 1 : (rh == 29) ? 30 : (rh == 30) ? 0 : 31;
    int rowid = d * 32 + h;
    int head = blockIdx.y;
    int rowbase = rowid * 64;
    int hoff = head * 64;
    int wave = tid >> 6, lane = tid & 63;
    int lm = lane & 15, lq = lane >> 4;
    bf16* pb = (bf16*)(smem + wave * 8192);    // per-wave P [64][64], XOR-swizzled

    // stage Q tile [64 tokens][64 dims]
    for (int i = tid; i < 512; i += 256) {
        int row = i >> 3, sub = i & 7;
        *(uint4*)&qs[row * 80 + sub * 8] =
            *(const uint4*)&qkv[(size_t)(rowbase + row) * 1536 + hoff + sub * 8];
    }
    __syncthreads();
    s8v qf[4][2];
#pragma unroll
    for (int mi = 0; mi < 4; mi++)
#pragma unroll
        for (int c = 0; c < 2; c++)
            qf[mi][c] = *(const s8v*)&qs[(mi * 16 + lm) * 80 + c * 32 + lq * 8];
    __syncthreads();   // qs consumed; pb (aliasing qs) may now be written

    // pre-zero this wave's P tile (8KB); cols never claimed by a lane stay 0 forever
    {
        uint4 z{0u, 0u, 0u, 0u};
#pragma unroll
        for (int i = 0; i < 8; i++) ((uint4*)pb)[lane + i * 64] = z;
    }

    f4v Oa[4][4];
#pragma unroll
    for (int i = 0; i < 4; i++)
#pragma unroll
        for (int j = 0; j < 4; j++) Oa[i][j] = f4v{0.f, 0.f, 0.f, 0.f};
    float mr[4][4], lr[4][4];
#pragma unroll
    for (int i = 0; i < 4; i++)
#pragma unroll
        for (int j = 0; j < 4; j++) { mr[i][j] = -1e30f; lr[i][j] = 0.f; }

    for (int idx = wave; idx < 35; idx += 4) {
        int dz = idx / 7 - 2, dy = idx % 7 - 3;
        int zz = d + dz, yy = h + dy;
        if ((unsigned)zz >= 4u || (unsigned)yy >= 32u) continue;
        int kbase = (zz * 32 + yy) * 64;
        // K loads for this offset
        s8v kf[4][2];
#pragma unroll
        for (int ni = 0; ni < 4; ni++)
#pragma unroll
            for (int c = 0; c < 2; c++)
                kf[ni][c] = *(const s8v*)&qkv[(size_t)(kbase + ni * 16 + lm) * 1536 + 512 + hoff + c * 32 + lq * 8];
        // per-mi QK^T + band-aware softmax interleave
#pragma unroll
        for (int mi = 0; mi < 4; mi++) {
            f4v s[4];
#pragma unroll
            for (int ni = 0; ni < 4; ni++) s[ni] = f4v{0.f, 0.f, 0.f, 0.f};
            __builtin_amdgcn_s_setprio(1);
#pragma unroll
            for (int c = 0; c < 2; c++)
#pragma unroll
                for (int ni = 0; ni < 4; ni++)
                    s[ni] = __builtin_amdgcn_mfma_f32_16x16x32_bf16(qf[mi][c], kf[ni][c], s[ni], 0, 0, 0);
            __builtin_amdgcn_s_setprio(0);
#pragma unroll
            for (int r = 0; r < 4; r++) {
                int w0 = mi * 16 + lq * 4 + r;
                float s0v = s[0][r], s1v = s[1][r], s2v = s[2][r], s3v = s[3][r];
                // unique candidate ni for this lane (band 7 < 16 apart)
                int t = w0 + 8 - lm;
                int niq = (t < 0) ? 0 : (t >> 4);
                niq = (niq > 3) ? 3 : niq;
                float vlo = (niq & 1) ? s1v : s0v;
                float vhi = (niq & 1) ? s3v : s2v;
                float v = (niq & 2) ? vhi : vlo;
                int col = (niq << 4) | lm;
                int dlt = col - w0;
                float vv = ((unsigned)(dlt + 3) <= 6u) ? v * 0.125f : -1e30f;
                float rm = vv;
#pragma unroll
                for (int off = 1; off <= 8; off <<= 1)
                    rm = fmaxf(rm, __shfl_xor(rm, off));
                float mo = mr[mi][r];
                float mn = mo;
                if (__any(rm > mo)) {      // rescale only when some row's max grew
                    mn = fmaxf(mo, rm);
                    float al = __expf(mo - mn);
                    mr[mi][r] = mn;
                    lr[mi][r] *= al;
#pragma unroll
                    for (int nd = 0; nd < 4; nd++)
                        Oa[mi][nd][r] *= al;
                }
                float p = __expf(vv - mn); // invalid lanes: exp(-1e30-mn) = 0
                float rs = p;
#pragma unroll
                for (int off = 1; off <= 8; off <<= 1)
                    rs += __shfl_xor(rs, off);
                lr[mi][r] += rs;
                pb[(w0 << 6) + (col ^ ((w0 & 7) << 3))] = __float2bfloat16(p);
            }
        }
        // V loads (issued before the LDS drain so they overlap it + the pf reads)
        s8v vf[4][2];
#pragma unroll
        for (int nd = 0; nd < 4; nd++)
#pragma unroll
            for (int c = 0; c < 2; c++)
                vf[nd][c] = *(const s8v*)&vT[(size_t)(hoff + nd * 16 + lm) * 8192 + kbase + c * 32 + lq * 8];
        __asm__ __volatile__("s_waitcnt lgkmcnt(0)" ::: "memory");
        __builtin_amdgcn_sched_barrier(0);
        // O += P V
        {
            s8v pf[4][2];
#pragma unroll
            for (int mi = 0; mi < 4; mi++)
#pragma unroll
                for (int c = 0; c < 2; c++)
                    pf[mi][c] = *(const s8v*)&pb[((mi * 16 + lm) << 6) + ((c * 32 + lq * 8) ^ ((lm & 7) << 3))];
            __builtin_amdgcn_s_setprio(1);
#pragma unroll
            for (int c = 0; c < 2; c++)
#pragma unroll
                for (int mi = 0; mi < 4; mi++)
#pragma unroll
                    for (int nd = 0; nd < 4; nd++)
                        Oa[mi][nd] = __builtin_amdgcn_mfma_f32_16x16x32_bf16(pf[mi][c], vf[nd][c], Oa[mi][nd], 0, 0, 0);
            __builtin_amdgcn_s_setprio(0);
        }
    }
    // publish per-wave m,l
    if (lm == 0) {
#pragma unroll
        for (int mi = 0; mi < 4; mi++)
#pragma unroll
            for (int r = 0; r < 4; r++) {
                int row = mi * 16 + lq * 4 + r;
                mlb[wave * 128 + row] = mr[mi][r];
                mlb[wave * 128 + 64 + row] = lr[mi][r];
            }
    }
    __syncthreads();
    // sequential cross-wave combine into obuf
    for (int wv = 0; wv < 4; wv++) {
        if (wave == wv) {
#pragma unroll
            for (int mi = 0; mi < 4; mi++)
#pragma unroll
                for (int r = 0; r < 4; r++) {
                    int row = mi * 16 + lq * 4 + r;
                    float M = fmaxf(fmaxf(mlb[row], mlb[128 + row]),
                                    fmaxf(mlb[256 + row], mlb[384 + row]));
                    float sc = __expf(mr[mi][r] - M);
#pragma unroll
                    for (int nd = 0; nd < 4; nd++) {
                        int ci = row * 65 + nd * 16 + lm;
                        float add = Oa[mi][nd][r] * sc;
                        obuf[ci] = (wv == 0) ? add : (obuf[ci] + add);
                    }
                }
        }
        __syncthreads();
    }
    // final normalize + coalesced store
    {
        int row = tid >> 2, cb = (tid & 3) * 16;
        float m0 = mlb[row], m1 = mlb[128 + row], m2 = mlb[256 + row], m3 = mlb[384 + row];
        float M = fmaxf(fmaxf(m0, m1), fmaxf(m2, m3));
        float L = mlb[64 + row] * __expf(m0 - M) + mlb[192 + row] * __expf(m1 - M)
                + mlb[320 + row] * __expf(m2 - M) + mlb[448 + row] * __expf(m3 - M);
        float inv = 1.f / L;
        union { uint4 u[2]; unsigned short hs[16]; } pk;
#pragma unroll
        for (int j = 0; j < 16; j++)
            pk.hs[j] = bfbits(obuf[row * 65 + cb + j] * inv);
        *(uint4*)&o[(size_t)(rowbase + row) * 512 + hoff + cb] = pk.u[0];
        *(uint4*)&o[(size_t)(rowbase + row) * 512 + hoff + cb + 8] = pk.u[1];
    }
}

// ---------------- final transpose: lat [P,512] fp32 -> out planar [512,P] ----------------
__global__ __launch_bounds__(256) void tout_k(const float* __restrict__ lat, float* __restrict__ out)
{
    __shared__ float t[64][65];
    int p0 = blockIdx.x * 64, c0 = blockIdx.y * 64;
    for (int i = threadIdx.x; i < 4096; i += 256) {
        int r = i >> 6, cc = i & 63;
        t[r][cc] = lat[(size_t)(p0 + r) * 512 + c0 + cc];
    }
    __syncthreads();
    for (int i = threadIdx.x; i < 4096; i += 256) {
        int cc = i >> 6, r = i & 63;
        out[(size_t)(c0 + cc) * 8192 + p0 + r] = t[r][cc];
    }
}

extern "C" void kernel_launch(void* const* d_in, const int* in_sizes, int n_in,
                              void* d_out, int out_size, void* d_ws, size_t ws_size,
                              hipStream_t stream)
{
    const float* x2d = (const float*)d_in[0];
    const float* x3d = (const float*)d_in[1];
    const float* sw0 = (const float*)d_in[2];
    const float* sb0 = (const float*)d_in[3];
    const float* sw1 = (const float*)d_in[4];
    const float* sb1 = (const float*)d_in[5];
    const float* sw2 = (const float*)d_in[6];
    const float* sb2 = (const float*)d_in[7];
    const float* pw0 = (const float*)d_in[8];
    const float* pb0 = (const float*)d_in[9];
    const float* pw1 = (const float*)d_in[10];
    const float* pb1 = (const float*)d_in[11];
    const float* pw2 = (const float*)d_in[12];
    const float* pb2 = (const float*)d_in[13];
    const float* latw = (const float*)d_in[14];
    const float* latb = (const float*)d_in[15];
    const float* lng = (const float*)d_in[16];
    const float* lnb = (const float*)d_in[17];
    const float* qkvw = (const float*)d_in[18];
    const float* qkvb = (const float*)d_in[19];
    const float* projw = (const float*)d_in[20];
    const float* projb = (const float*)d_in[21];
    float* outp = (float*)d_out;

    char* ws = (char*)d_ws;
    bf16* p0pad = (bf16*)(ws + 0);              // [12][128][258][128] = 101,449,728
    bf16* wr3d2 = (bf16*)(ws + 101449728ull);
    bf16* wr3d3 = (bf16*)(ws + 103219200ull);
    bf16* wr2d2 = (bf16*)(ws + 110297088ull);
    bf16* wr2d3 = (bf16*)(ws + 110886912ull);
    bf16* qkvt  = (bf16*)(ws + 113246208ull);
    bf16* projt = (bf16*)(ws + 117964800ull);
    bf16* latbf = (bf16*)(ws + 119537664ull);
    bf16* w13d  = (bf16*)(ws + 120061952ull);
    bf16* w12d  = (bf16*)(ws + 120102912ull);
    bf16* p1pad = (bf16*)(ws + 120127488ull);   // [6][64][130][256]
    bf16* s0pad = (bf16*)(ws + 145686528ull);   // [128][258][128]
    bf16* s1pad = (bf16*)(ws + 154140672ull);   // [64][130][256]
    bf16* featsT= (bf16*)(ws + 158400512ull);   // [8192][512]
    float* lat  = (float*)(ws + 166789120ull);  // [8192][512] fp32 -> 183,566,336 total
    bf16* A3 = (bf16*)(ws + 120127488ull);      // im2col 3d half (over p1..lat)
    bf16* A2 = (bf16*)(ws + 158400512ull);      // im2col 2d (over featsT)
    bf16* ybf    = (bf16*)(ws + 0);             //  8,388,608
    bf16* qkvbuf = (bf16*)(ws + 8388608ull);    // 25,165,824
    bf16* attno  = (bf16*)(ws + 33554432ull);   //  8,388,608
    bf16* vT     = (bf16*)(ws + 41943040ull);   //  8,388,608 [512][8192]

    // 1) weight prep
    wprep_k<<<3456, 256, 0, stream>>>(pw1, wr3d2, 256, 128, 27);
    wprep_k<<<13824, 256, 0, stream>>>(pw2, wr3d3, 512, 256, 27);
    wprep_k<<<1152, 256, 0, stream>>>(sw1, wr2d2, 256, 128, 9);
    wprep_k<<<4608, 256, 0, stream>>>(sw2, wr2d3, 512, 256, 9);
    for (int r = 0; r < 3; r++) {
        tprep_k<<<3072, 256, 0, stream>>>(qkvw + (size_t)r * 786432, qkvt + (size_t)r * 786432, 512, 1536);
        tprep_k<<<1024, 256, 0, stream>>>(projw + (size_t)r * 262144, projt + (size_t)r * 262144, 512, 512);
    }
    cast_k<<<1024, 256, 0, stream>>>(latw, latbf, 262144);
    w1prep_k<<<80, 256, 0, stream>>>(pw0, w13d, 128, 5, 27, 160);
    w1prep_k<<<48, 256, 0, stream>>>(sw0, w12d, 128, 8, 9, 96);

    // 2) zero p0pad (halo)
    fill0_k<<<24768, 256, 0, stream>>>((uint4*)p0pad, 6340608);

    // 3) conv3d#1 via im2col + MFMA GEMM, two od-halves
    im2col3d_k<<<15360, 256, 0, stream>>>(x3d, A3, 0);
    conv1_gemm<<<1536, 256, 0, stream>>>(A3, w13d, pb0, p0pad, 196608, 160, 0);
    im2col3d_k<<<15360, 256, 0, stream>>>(x3d, A3, 6);
    conv1_gemm<<<1536, 256, 0, stream>>>(A3, w13d, pb0, p0pad, 196608, 160, 768);

    // 4) zero p1pad+s0pad+s1pad (halos); then conv2d#1
    fill0_k<<<9344, 256, 0, stream>>>((uint4*)p1pad, 2392064);
    im2col2d_k<<<1536, 256, 0, stream>>>(x2d, A2);
    conv1_gemm<<<256, 256, 0, stream>>>(A2, w12d, sb0, s0pad, 32768, 96, 0);

    // 5) conv chains (#2/#3) — 1D grids, XCD-swizzled inside
    conv_mfma2<128, 1><<<dim3(128), 256, 0, stream>>>(s0pad, wr2d2, sb1, s1pad, 1, 128, 258, 128, 64, 256, 130, 1, 2);
    conv_mfma2<64, 1><<<dim3(128), 256, 0, stream>>>(s1pad, wr2d3, sb2, featsT + (size_t)6144 * 512, 1, 64, 130, 256, 32, 512, 64, 0, 4);
    conv_mfma2<128, 3><<<dim3(768), 256, 0, stream>>>(p0pad, wr3d2, pb1, p1pad, 12, 128, 258, 128, 64, 256, 130, 1, 2);
    conv_mfma2<64, 3><<<dim3(384), 256, 0, stream>>>(p1pad, wr3d3, pb2, featsT, 6, 64, 130, 256, 32, 512, 64, 0, 4);

    // 6) lateral 1x1 conv
    gemm_bt<float, 0, 0><<<dim3(4, 64), 256, 0, stream>>>(featsT, latbf, latb, lat, nullptr, nullptr, 8192, 512, 512);

    // 7) 3 attention rounds
    for (int r = 0; r < 3; r++) {
        ln_k<<<2048, 256, 0, stream>>>(lat, lng + r * 512, lnb + r * 512, ybf);
        gemm_bt<bf16, 0, 1><<<dim3(12, 64), 256, 0, stream>>>(ybf, qkvt + (size_t)r * 786432, qkvb + r * 1536,
                                                              qkvbuf, nullptr, vT, 8192, 1536, 512);
        natt_mfma<<<dim3(128, 8), 256, 0, stream>>>(qkvbuf, vT, attno);
        gemm_bt<float, 1, 0><<<dim3(4, 64), 256, 0, stream>>>(attno, projt + (size_t)r * 262144, projb + r * 512,
                                                              lat, lat, nullptr, 8192, 512, 512);
    }

    // 8) transpose to planar output [512][4][32][64]
    tout_k<<<dim3(128, 8), 256, 0, stream>>>(lat, outp);
}

// Round 4
// 1390.900 us; speedup vs baseline: 1.1033x; 1.1033x over previous
//
#include <hip/hip_runtime.h>
#include <hip/hip_bf16.h>
#include <math.h>

typedef __hip_bfloat16 bf16;
typedef __attribute__((ext_vector_type(8))) short s8v;
typedef __attribute__((ext_vector_type(4))) float f4v;

__device__ __forceinline__ float ldf(const float* p) { return *p; }
__device__ __forceinline__ float ldf(const bf16* p) { return __bfloat162float(*p); }
__device__ __forceinline__ void stf(float* p, float v) { *p = v; }
__device__ __forceinline__ void stf(bf16* p, float v) { *p = __float2bfloat16(v); }

__device__ __forceinline__ float gelu_tanh(float x) {
    float x3 = x * x * x;
    return 0.5f * x * (1.f + tanhf(0.7978845608028654f * (x + 0.044715f * x3)));
}
__device__ __forceinline__ unsigned short bfbits(float x) {
    bf16 t = __float2bfloat16(x);
    return *(unsigned short*)&t;
}

// async global->LDS 16B: LDS dest must be wave-uniform base (+ lane*16 by HW);
// global src is per-lane.
__device__ __forceinline__ void gload16(const bf16* g, bf16* l)
{
    __builtin_amdgcn_global_load_lds(
        (const __attribute__((address_space(1))) unsigned int*)g,
        (__attribute__((address_space(3))) unsigned int*)l,
        16, 0, 0);
}

// ---------------- zero fill (16B granules) ----------------
__global__ __launch_bounds__(256) void fill0_k(uint4* __restrict__ p, int n16)
{
    int i = blockIdx.x * 256 + threadIdx.x;
    if (i < n16) p[i] = uint4{0u, 0u, 0u, 0u};
}

// ---------------- weight reorder: fp32 [OC][IC][T] -> bf16 [T][OC][IC] ----------------
__global__ __launch_bounds__(256) void wprep_k(const float* __restrict__ w, bf16* __restrict__ wr,
                                               int OC, int IC, int T)
{
    int i = blockIdx.x * 256 + threadIdx.x;
    if (i >= OC * IC * T) return;
    int t = i % T; int rem = i / T; int ic = rem % IC; int oc = rem / IC;
    wr[((size_t)t * OC + oc) * IC + ic] = __float2bfloat16(w[i]);
}

// ---------------- conv#1 weight prep: fp32 [OC][nic][ntap] -> bf16 [OC][Kp], k=tap*nic+ic ----------------
__global__ __launch_bounds__(256) void w1prep_k(const float* __restrict__ w, bf16* __restrict__ o,
                                                int OC, int nic, int ntap, int Kp)
{
    int i = blockIdx.x * 256 + threadIdx.x;
    if (i >= OC * Kp) return;
    int oc = i / Kp, k = i - oc * Kp;
    float v = 0.f;
    if (k < nic * ntap) {
        int tap = k / nic, ic = k - tap * nic;
        v = w[((size_t)oc * nic + ic) * ntap + tap];
    }
    o[i] = __float2bfloat16(v);
}

// ---------------- transpose cast: fp32 [K][N] -> bf16 [N][K] ----------------
__global__ __launch_bounds__(256) void tprep_k(const float* __restrict__ w, bf16* __restrict__ wt,
                                               int K, int N)
{
    int i = blockIdx.x * 256 + threadIdx.x;
    if (i >= K * N) return;
    int n = i % N, k = i / N;
    wt[(size_t)n * K + k] = __float2bfloat16(w[i]);
}

// ---------------- plain cast fp32 -> bf16 ----------------
__global__ __launch_bounds__(256) void cast_k(const float* __restrict__ w, bf16* __restrict__ o, int n)
{
    int i = blockIdx.x * 256 + threadIdx.x;
    if (i < n) o[i] = __float2bfloat16(w[i]);
}

// ---------------- im2col for conv3d#1: x3d fp32 [5][24][256][512] -> A bf16 [196608][160] ----------------
__global__ __launch_bounds__(256) void im2col3d_k(const float* __restrict__ x, bf16* __restrict__ A, int od0)
{
    int gid = blockIdx.x * 256 + threadIdx.x;  // 196608*20
    int m = gid / 20, kg = gid - 20 * (gid / 20);
    int ow = m & 255, rowid = m >> 8;
    int oh = rowid & 127, od = od0 + (rowid >> 7);
    int iz0 = 2 * od - 1, iy0 = 2 * oh - 1, ix0 = 2 * ow - 1;
    union { uint4 u; unsigned short h[8]; } pk;
#pragma unroll
    for (int j = 0; j < 8; j++) {
        int k = kg * 8 + j;
        float v = 0.f;
        if (k < 135) {
            int tap = k / 5, ic = k - tap * 5;
            int kz = tap / 9, r = tap - kz * 9;
            int ky = r / 3, kx = r - ky * 3;
            int iz = iz0 + kz, iy = iy0 + ky, ix = ix0 + kx;
            if ((unsigned)iz < 24u && (unsigned)iy < 256u && (unsigned)ix < 512u)
                v = x[(((size_t)ic * 24 + iz) * 256 + iy) * 512 + ix];
        }
        pk.h[j] = bfbits(v);
    }
    *(uint4*)&A[(size_t)m * 160 + kg * 8] = pk.u;
}

// ---------------- im2col for conv2d#1: x2d fp32 [8][256][512] -> A bf16 [32768][96] ----------------
__global__ __launch_bounds__(256) void im2col2d_k(const float* __restrict__ x, bf16* __restrict__ A)
{
    int gid = blockIdx.x * 256 + threadIdx.x;  // 32768*12
    int m = gid / 12, kg = gid - 12 * (gid / 12);
    int ow = m & 255, oh = m >> 8;
    int iy0 = 2 * oh - 1, ix0 = 2 * ow - 1;
    union { uint4 u; unsigned short h[8]; } pk;
#pragma unroll
    for (int j = 0; j < 8; j++) {
        int k = kg * 8 + j;
        float v = 0.f;
        if (k < 72) {
            int tap = k >> 3, ic = k & 7;
            int ky = tap / 3, kx = tap - ky * 3;
            int iy = iy0 + ky, ix = ix0 + kx;
            if ((unsigned)iy < 256u && (unsigned)ix < 512u)
                v = x[((size_t)ic * 256 + iy) * 512 + ix];
        }
        pk.h[j] = bfbits(v);
    }
    *(uint4*)&A[(size_t)m * 96 + kg * 8] = pk.u;
}

// ---------------- conv#1 GEMM: C = A[M][Kp] x W[128][Kp]^T, +bias, GELU, padded NHWC store ----------------
__global__ __launch_bounds__(256) void conv1_gemm(
    const bf16* __restrict__ A, const bf16* __restrict__ W, const float* __restrict__ bias,
    bf16* __restrict__ out, int M, int Kp, int rowOff)
{
    __shared__ __align__(16) bf16 As[128 * 32];
    __shared__ __align__(16) bf16 Bs[128 * 32];
    int tid = threadIdx.x;
    int m0 = blockIdx.x * 128;
    int wave = tid >> 6, lane = tid & 63;
    int wb = tid & 192;
    int wm = (wave >> 1) * 64, wn = (wave & 1) * 64;
    int lm = lane & 15, lq = lane >> 4;
    f4v acc[4][4];
#pragma unroll
    for (int i = 0; i < 4; i++)
#pragma unroll
        for (int j = 0; j < 4; j++) acc[i][j] = f4v{0.f, 0.f, 0.f, 0.f};
    for (int k0 = 0; k0 < Kp; k0 += 32) {
        __syncthreads();
#pragma unroll
        for (int c = 0; c < 2; c++) {
            int i = c * 256 + tid;
            int row = i >> 2, kq = i & 3;
            gload16(&A[(size_t)(m0 + row) * Kp + k0 + kq * 8], &As[(c * 256 + wb) * 8]);
            gload16(&W[(size_t)row * Kp + k0 + kq * 8], &Bs[(c * 256 + wb) * 8]);
        }
        __syncthreads();
        s8v af[4], bfr[4];
#pragma unroll
        for (int mi = 0; mi < 4; mi++) af[mi] = *(const s8v*)&As[(wm + mi * 16 + lm) * 32 + lq * 8];
#pragma unroll
        for (int ni = 0; ni < 4; ni++) bfr[ni] = *(const s8v*)&Bs[(wn + ni * 16 + lm) * 32 + lq * 8];
#pragma unroll
        for (int mi = 0; mi < 4; mi++)
#pragma unroll
            for (int ni = 0; ni < 4; ni++)
                acc[mi][ni] = __builtin_amdgcn_mfma_f32_16x16x32_bf16(af[mi], bfr[ni], acc[mi][ni], 0, 0, 0);
    }
#pragma unroll
    for (int mi = 0; mi < 4; mi++)
#pragma unroll
        for (int ni = 0; ni < 4; ni++)
#pragma unroll
            for (int r = 0; r < 4; r++) {
                int m = m0 + wm + mi * 16 + lq * 4 + r;
                int n = wn + ni * 16 + lm;
                int row = rowOff + (m >> 8), x = m & 255;
                float v = acc[mi][ni][r] + bias[n];
                out[((size_t)row * 258 + 1 + x) * 128 + n] = __float2bfloat16(gelu_tanh(v));
            }
}

// ================= MFMA tap-GEMM conv (#2/#3): 3 kx-taps per barrier =================
// 1D grid with XCD-aware swizzle.
template <int BM, int KD>
__global__ __launch_bounds__(256) void conv_mfma2(
    const bf16* __restrict__ in, const bf16* __restrict__ wr, const float* __restrict__ bias,
    bf16* __restrict__ out, int ID, int IH, int IWp, int IC,
    int OH, int OC, int OWS, int outPad, int nx)
{
    constexpr int NI = (BM == 128) ? 4 : 2;
    __shared__ __align__(16) bf16 As[3 * BM * 32];
    __shared__ __align__(16) bf16 Bs[3 * 128 * 32];
    int tid = threadIdx.x;
    int nwg = gridDim.x;                    // always a multiple of 8
    int bl = blockIdx.x;
    int swz = (bl & 7) * (nwg >> 3) + (bl >> 3);
    int n0 = (swz % nx) * 128;
    int rowid = swz / nx;
    int od = rowid / OH, oh = rowid % OH;
    int wave = tid >> 6, lane = tid & 63;
    int wb = tid & 192;                     // wave*64
    int wm = (BM == 128) ? (wave >> 1) * 64 : 0;
    int wn = (BM == 128) ? (wave & 1) * 64 : wave * 32;
    int lm = lane & 15, lq = lane >> 4;
    f4v acc[4][NI];
#pragma unroll
    for (int i = 0; i < 4; i++)
#pragma unroll
        for (int j = 0; j < NI; j++) acc[i][j] = f4v{0.f, 0.f, 0.f, 0.f};

    for (int kz = 0; kz < KD; kz++) {
        int iz = (KD == 3) ? (2 * od + kz - 1) : 0;
        if ((unsigned)iz >= (unsigned)ID) continue;
        for (int ky = 0; ky < 3; ky++) {
            int iy = 2 * oh + ky - 1;
            if ((unsigned)iy >= (unsigned)IH) continue;
            const bf16* inrow = in + ((size_t)iz * IH + iy) * IWp * IC;
            const bf16* wbase = wr + (size_t)((kz * 3 + ky) * 3) * OC * IC;
            for (int kb = 0; kb < IC; kb += 32) {
                __syncthreads();
#pragma unroll
                for (int c = 0; c < (3 * BM) / 64; c++) {
                    int i = c * 256 + tid;
                    int kx = i / (BM * 4);
                    int r = i - kx * (BM * 4);
                    int m = r >> 2, sub = r & 3;
                    gload16(&inrow[(size_t)(2 * m + kx) * IC + kb + sub * 8],
                            &As[(c * 256 + wb) * 8]);
                }
#pragma unroll
                for (int c = 0; c < 6; c++) {
                    int i = c * 256 + tid;
                    int t3 = i >> 9, r = i & 511, n = r >> 2, sub = r & 3;
                    gload16(&wbase[((size_t)t3 * OC + n0 + n) * IC + kb + sub * 8],
                            &Bs[(c * 256 + wb) * 8]);
                }
                __syncthreads();
#pragma unroll
                for (int kx = 0; kx < 3; kx++) {
                    s8v af[4], bfr[NI];
#pragma unroll
                    for (int mi = 0; mi < 4; mi++)
                        af[mi] = *(const s8v*)&As[(kx * BM + wm + mi * 16 + lm) * 32 + lq * 8];
#pragma unroll
                    for (int ni = 0; ni < NI; ni++)
                        bfr[ni] = *(const s8v*)&Bs[(kx * 128 + wn + ni * 16 + lm) * 32 + lq * 8];
#pragma unroll
                    for (int mi = 0; mi < 4; mi++)
#pragma unroll
                        for (int ni = 0; ni < NI; ni++)
                            acc[mi][ni] = __builtin_amdgcn_mfma_f32_16x16x32_bf16(af[mi], bfr[ni], acc[mi][ni], 0, 0, 0);
                }
            }
        }
    }
    size_t orowbase = ((size_t)rowid * OWS + outPad) * OC;
#pragma unroll
    for (int mi = 0; mi < 4; mi++)
#pragma unroll
        for (int ni = 0; ni < NI; ni++)
#pragma unroll
            for (int r = 0; r < 4; r++) {
                int m = wm + mi * 16 + lq * 4 + r;
                int n = n0 + wn + ni * 16 + lm;
                float v = acc[mi][ni][r] + bias[n];
                out[orowbase + (size_t)m * OC + n] = __float2bfloat16(gelu_tanh(v));
            }
}

// ================= MFMA GEMM: C[M,N] = A[M,K] * Bt[N,K]^T + bias (+res) (+vT side-write) ==========
template <typename OutT, int RES, int VT>
__global__ __launch_bounds__(256) void gemm_bt(
    const bf16* __restrict__ A, const bf16* __restrict__ Bt, const float* __restrict__ bias,
    OutT* __restrict__ C, const float* __restrict__ res, bf16* __restrict__ vt,
    int M, int N, int K)
{
    __shared__ __align__(16) bf16 As[128 * 32];
    __shared__ __align__(16) bf16 Bs[128 * 32];
    int tid = threadIdx.x;
    int n0 = blockIdx.x * 128, m0 = blockIdx.y * 128;
    int wave = tid >> 6, lane = tid & 63;
    int wb = tid & 192;
    int wm = (wave >> 1) * 64, wn = (wave & 1) * 64;
    int lm = lane & 15, lq = lane >> 4;
    f4v acc[4][4];
#pragma unroll
    for (int i = 0; i < 4; i++)
#pragma unroll
        for (int j = 0; j < 4; j++) acc[i][j] = f4v{0.f, 0.f, 0.f, 0.f};
    for (int k0 = 0; k0 < K; k0 += 32) {
        __syncthreads();
#pragma unroll
        for (int c = 0; c < 2; c++) {
            int i = c * 256 + tid;
            int row = i >> 2, kq = i & 3;
            gload16(&A[(size_t)(m0 + row) * K + k0 + kq * 8], &As[(c * 256 + wb) * 8]);
            gload16(&Bt[(size_t)(n0 + row) * K + k0 + kq * 8], &Bs[(c * 256 + wb) * 8]);
        }
        __syncthreads();
        s8v af[4], bfr[4];
#pragma unroll
        for (int mi = 0; mi < 4; mi++) af[mi] = *(const s8v*)&As[(wm + mi * 16 + lm) * 32 + lq * 8];
#pragma unroll
        for (int ni = 0; ni < 4; ni++) bfr[ni] = *(const s8v*)&Bs[(wn + ni * 16 + lm) * 32 + lq * 8];
#pragma unroll
        for (int mi = 0; mi < 4; mi++)
#pragma unroll
            for (int ni = 0; ni < 4; ni++)
                acc[mi][ni] = __builtin_amdgcn_mfma_f32_16x16x32_bf16(af[mi], bfr[ni], acc[mi][ni], 0, 0, 0);
    }
#pragma unroll
    for (int mi = 0; mi < 4; mi++)
#pragma unroll
        for (int ni = 0; ni < 4; ni++) {
            int n = n0 + wn + ni * 16 + lm;
            int mbase = m0 + wm + mi * 16 + lq * 4;
            float b = bias[n];
            if (VT && n >= 1024) {
                ushort4 pk;
                pk.x = bfbits(acc[mi][ni][0] + b);
                pk.y = bfbits(acc[mi][ni][1] + b);
                pk.z = bfbits(acc[mi][ni][2] + b);
                pk.w = bfbits(acc[mi][ni][3] + b);
                *(ushort4*)&vt[(size_t)(n - 1024) * 8192 + mbase] = pk;
            }
#pragma unroll
            for (int r = 0; r < 4; r++) {
                int m = mbase + r;
                float v = acc[mi][ni][r] + b;
                if (RES) v += res[(size_t)m * N + n];
                stf(&C[(size_t)m * N + n], v);
            }
        }
}

// ---------------- LayerNorm: lat fp32 [P,512] -> y bf16 [P,512]; one wave per token ----------------
__global__ __launch_bounds__(256) void ln_k(
    const float* __restrict__ lat, const float* __restrict__ g, const float* __restrict__ b,
    bf16* __restrict__ y)
{
    int tok = blockIdx.x * 4 + (threadIdx.x >> 6);
    int lane = threadIdx.x & 63;
    const float4* row = (const float4*)&lat[(size_t)tok * 512 + lane * 8];
    float4 a = row[0], c = row[1];
    float s = a.x + a.y + a.z + a.w + c.x + c.y + c.z + c.w;
    float ss = a.x * a.x + a.y * a.y + a.z * a.z + a.w * a.w
             + c.x * c.x + c.y * c.y + c.z * c.z + c.w * c.w;
#pragma unroll
    for (int off = 32; off; off >>= 1) {
        s += __shfl_xor(s, off);
        ss += __shfl_xor(ss, off);
    }
    float mu = s * (1.f / 512.f);
    float var = ss * (1.f / 512.f) - mu * mu;
    float rstd = rsqrtf(var + 1e-5f);
    const float4* gp = (const float4*)&g[lane * 8];
    const float4* bp = (const float4*)&b[lane * 8];
    float4 g0 = gp[0], g1 = gp[1], b0 = bp[0], b1 = bp[1];
    union { uint4 u; unsigned short h[8]; } pk;
    pk.h[0] = bfbits((a.x - mu) * rstd * g0.x + b0.x);
    pk.h[1] = bfbits((a.y - mu) * rstd * g0.y + b0.y);
    pk.h[2] = bfbits((a.z - mu) * rstd * g0.z + b0.z);
    pk.h[3] = bfbits((a.w - mu) * rstd * g0.w + b0.w);
    pk.h[4] = bfbits((c.x - mu) * rstd * g1.x + b1.x);
    pk.h[5] = bfbits((c.y - mu) * rstd * g1.y + b1.y);
    pk.h[6] = bfbits((c.z - mu) * rstd * g1.z + b1.z);
    pk.h[7] = bfbits((c.w - mu) * rstd * g1.w + b1.w);
    *(uint4*)&y[(size_t)tok * 512 + lane * 8] = pk.u;
}

// ================= MFMA flash-style neighborhood attention =================
// grid (128 rows, 8 heads); block 256 = 4 waves; wave handles (dz,dy) idx = wave + 4t.
// Register-pressure-shaped: Q fragments live in a persistent LDS tile ([64][88],
// 2-way-free banking) and are re-read per mi; PV reads P per-c-half. Band-aware
// softmax (1 exp / row / lane), defer-max rescale skip, pre-zeroed swizzled P tile,
// heavy-block-first remap. NO forced occupancy bound (r3's forced 3-wave bound
// caused catastrophic scratch spill: VGPR 84, +280 MB HBM traffic).
__global__ __launch_bounds__(256) void natt_mfma(
    const bf16* __restrict__ qkv, const bf16* __restrict__ vT, bf16* __restrict__ o)
{
    __shared__ __align__(16) char smem[46080];
    bf16* qs = (bf16*)smem;                    // [64][88] bf16, persistent
    float* obuf = (float*)(smem + 11264);      // [64][65] fp32 (epilogue, aliases pb w0/w1)
    float* mlb = (float*)(smem + 44032);       // [4 waves][2][64]
    int tid = threadIdx.x;
    // work-ordered remap: interior (heavy) blocks start first; corners drain last.
    int bx = blockIdx.x;
    int rd = bx >> 5, rh = bx & 31;
    int d = (rd == 0) ? 1 : (rd == 1) ? 2 : (rd == 2) ? 0 : 3;
    int h = (rh < 26) ? (rh + 3) : (rh == 26) ? 2 : (rh == 27) ? 29
          : (rh == 28) ? 1 : (rh == 29) ? 30 : (rh == 30) ? 0 : 31;
    int rowid = d * 32 + h;
    int head = blockIdx.y;
    int rowbase = rowid * 64;
    int hoff = head * 64;
    int wave = tid >> 6, lane = tid & 63;
    int lm = lane & 15, lq = lane >> 4;
    bf16* pb = (bf16*)(smem + 11264 + wave * 8192);  // per-wave P [64][64], XOR-swizzled

    // stage Q tile [64 tokens][64 dims] into qs[64][88]
    for (int i = tid; i < 512; i += 256) {
        int row = i >> 3, sub = i & 7;
        *(uint4*)&qs[row * 88 + sub * 8] =
            *(const uint4*)&qkv[(size_t)(rowbase + row) * 1536 + hoff + sub * 8];
    }
    // pre-zero this wave's P tile (8KB); cols never claimed by a lane stay 0 forever
    {
        uint4 z{0u, 0u, 0u, 0u};
#pragma unroll
        for (int i = 0; i < 8; i++) ((uint4*)pb)[lane + i * 64] = z;
    }
    __syncthreads();

    f4v Oa[4][4];
#pragma unroll
    for (int i = 0; i < 4; i++)
#pragma unroll
        for (int j = 0; j < 4; j++) Oa[i][j] = f4v{0.f, 0.f, 0.f, 0.f};
    float mr[4][4], lr[4][4];
#pragma unroll
    for (int i = 0; i < 4; i++)
#pragma unroll
        for (int j = 0; j < 4; j++) { mr[i][j] = -1e30f; lr[i][j] = 0.f; }

    for (int idx = wave; idx < 35; idx += 4) {
        int dz = idx / 7 - 2, dy = idx % 7 - 3;
        int zz = d + dz, yy = h + dy;
        if ((unsigned)zz >= 4u || (unsigned)yy >= 32u) continue;
        int kbase = (zz * 32 + yy) * 64;
        // K loads for this offset
        s8v kf[4][2];
#pragma unroll
        for (int ni = 0; ni < 4; ni++)
#pragma unroll
            for (int c = 0; c < 2; c++)
                kf[ni][c] = *(const s8v*)&qkv[(size_t)(kbase + ni * 16 + lm) * 1536 + 512 + hoff + c * 32 + lq * 8];
        // per-mi QK^T + band-aware softmax interleave (Q fragment re-read from LDS)
#pragma unroll
        for (int mi = 0; mi < 4; mi++) {
            s8v qfc[2];
            qfc[0] = *(const s8v*)&qs[(mi * 16 + lm) * 88 + lq * 8];
            qfc[1] = *(const s8v*)&qs[(mi * 16 + lm) * 88 + 32 + lq * 8];
            f4v s[4];
#pragma unroll
            for (int ni = 0; ni < 4; ni++) s[ni] = f4v{0.f, 0.f, 0.f, 0.f};
            __builtin_amdgcn_s_setprio(1);
#pragma unroll
            for (int c = 0; c < 2; c++)
#pragma unroll
                for (int ni = 0; ni < 4; ni++)
                    s[ni] = __builtin_amdgcn_mfma_f32_16x16x32_bf16(qfc[c], kf[ni][c], s[ni], 0, 0, 0);
            __builtin_amdgcn_s_setprio(0);
#pragma unroll
            for (int r = 0; r < 4; r++) {
                int w0 = mi * 16 + lq * 4 + r;
                float s0v = s[0][r], s1v = s[1][r], s2v = s[2][r], s3v = s[3][r];
                // unique candidate ni for this lane (band 7 < 16 apart)
                int t = w0 + 8 - lm;
                int niq = (t < 0) ? 0 : (t >> 4);
                niq = (niq > 3) ? 3 : niq;
                float vlo = (niq & 1) ? s1v : s0v;
                float vhi = (niq & 1) ? s3v : s2v;
                float v = (niq & 2) ? vhi : vlo;
                int col = (niq << 4) | lm;
                int dlt = col - w0;
                float vv = ((unsigned)(dlt + 3) <= 6u) ? v * 0.125f : -1e30f;
                float rm = vv;
#pragma unroll
                for (int off = 1; off <= 8; off <<= 1)
                    rm = fmaxf(rm, __shfl_xor(rm, off));
                float mo = mr[mi][r];
                float mn = mo;
                if (__any(rm > mo)) {      // rescale only when some row's max grew
                    mn = fmaxf(mo, rm);
                    float al = __expf(mo - mn);
                    mr[mi][r] = mn;
                    lr[mi][r] *= al;
#pragma unroll
                    for (int nd = 0; nd < 4; nd++)
                        Oa[mi][nd][r] *= al;
                }
                float p = __expf(vv - mn); // invalid lanes: exp(-1e30-mn) = 0
                float rs = p;
#pragma unroll
                for (int off = 1; off <= 8; off <<= 1)
                    rs += __shfl_xor(rs, off);
                lr[mi][r] += rs;
                pb[(w0 << 6) + (col ^ ((w0 & 7) << 3))] = __float2bfloat16(p);
            }
        }
        // V loads (both halves issued up front; vmcnt independent of the LDS drain)
        s8v vf[4][2];
#pragma unroll
        for (int nd = 0; nd < 4; nd++)
#pragma unroll
            for (int c = 0; c < 2; c++)
                vf[nd][c] = *(const s8v*)&vT[(size_t)(hoff + nd * 16 + lm) * 8192 + kbase + c * 32 + lq * 8];
        __asm__ __volatile__("s_waitcnt lgkmcnt(0)" ::: "memory");
        __builtin_amdgcn_sched_barrier(0);
        // O += P V  (P read per-c-half: 16 live pf regs instead of 32)
#pragma unroll
        for (int c = 0; c < 2; c++) {
            s8v pf[4];
#pragma unroll
            for (int mi = 0; mi < 4; mi++)
                pf[mi] = *(const s8v*)&pb[((mi * 16 + lm) << 6) + ((c * 32 + lq * 8) ^ ((lm & 7) << 3))];
            __builtin_amdgcn_s_setprio(1);
#pragma unroll
            for (int mi = 0; mi < 4; mi++)
#pragma unroll
                for (int nd = 0; nd < 4; nd++)
                    Oa[mi][nd] = __builtin_amdgcn_mfma_f32_16x16x32_bf16(pf[mi], vf[nd][c], Oa[mi][nd], 0, 0, 0);
            __builtin_amdgcn_s_setprio(0);
        }
    }
    // publish per-wave m,l
    if (lm == 0) {
#pragma unroll
        for (int mi = 0; mi < 4; mi++)
#pragma unroll
            for (int r = 0; r < 4; r++) {
                int row = mi * 16 + lq * 4 + r;
                mlb[wave * 128 + row] = mr[mi][r];
                mlb[wave * 128 + 64 + row] = lr[mi][r];
            }
    }
    __syncthreads();
    // sequential cross-wave combine into obuf
    for (int wv = 0; wv < 4; wv++) {
        if (wave == wv) {
#pragma unroll
            for (int mi = 0; mi < 4; mi++)
#pragma unroll
                for (int r = 0; r < 4; r++) {
                    int row = mi * 16 + lq * 4 + r;
                    float M = fmaxf(fmaxf(mlb[row], mlb[128 + row]),
                                    fmaxf(mlb[256 + row], mlb[384 + row]));
                    float sc = __expf(mr[mi][r] - M);
#pragma unroll
                    for (int nd = 0; nd < 4; nd++) {
                        int ci = row * 65 + nd * 16 + lm;
                        float add = Oa[mi][nd][r] * sc;
                        obuf[ci] = (wv == 0) ? add : (obuf[ci] + add);
                    }
                }
        }
        __syncthreads();
    }
    // final normalize + coalesced store
    {
        int row = tid >> 2, cb = (tid & 3) * 16;
        float m0 = mlb[row], m1 = mlb[128 + row], m2 = mlb[256 + row], m3 = mlb[384 + row];
        float M = fmaxf(fmaxf(m0, m1), fmaxf(m2, m3));
        float L = mlb[64 + row] * __expf(m0 - M) + mlb[192 + row] * __expf(m1 - M)
                + mlb[320 + row] * __expf(m2 - M) + mlb[448 + row] * __expf(m3 - M);
        float inv = 1.f / L;
        union { uint4 u[2]; unsigned short hs[16]; } pk;
#pragma unroll
        for (int j = 0; j < 16; j++)
            pk.hs[j] = bfbits(obuf[row * 65 + cb + j] * inv);
        *(uint4*)&o[(size_t)(rowbase + row) * 512 + hoff + cb] = pk.u[0];
        *(uint4*)&o[(size_t)(rowbase + row) * 512 + hoff + cb + 8] = pk.u[1];
    }
}

// ---------------- final transpose: lat [P,512] fp32 -> out planar [512,P] ----------------
__global__ __launch_bounds__(256) void tout_k(const float* __restrict__ lat, float* __restrict__ out)
{
    __shared__ float t[64][65];
    int p0 = blockIdx.x * 64, c0 = blockIdx.y * 64;
    for (int i = threadIdx.x; i < 4096; i += 256) {
        int r = i >> 6, cc = i & 63;
        t[r][cc] = lat[(size_t)(p0 + r) * 512 + c0 + cc];
    }
    __syncthreads();
    for (int i = threadIdx.x; i < 4096; i += 256) {
        int cc = i >> 6, r = i & 63;
        out[(size_t)(c0 + cc) * 8192 + p0 + r] = t[r][cc];
    }
}

extern "C" void kernel_launch(void* const* d_in, const int* in_sizes, int n_in,
                              void* d_out, int out_size, void* d_ws, size_t ws_size,
                              hipStream_t stream)
{
    const float* x2d = (const float*)d_in[0];
    const float* x3d = (const float*)d_in[1];
    const float* sw0 = (const float*)d_in[2];
    const float* sb0 = (const float*)d_in[3];
    const float* sw1 = (const float*)d_in[4];
    const float* sb1 = (const float*)d_in[5];
    const float* sw2 = (const float*)d_in[6];
    const float* sb2 = (const float*)d_in[7];
    const float* pw0 = (const float*)d_in[8];
    const float* pb0 = (const float*)d_in[9];
    const float* pw1 = (const float*)d_in[10];
    const float* pb1 = (const float*)d_in[11];
    const float* pw2 = (const float*)d_in[12];
    const float* pb2 = (const float*)d_in[13];
    const float* latw = (const float*)d_in[14];
    const float* latb = (const float*)d_in[15];
    const float* lng = (const float*)d_in[16];
    const float* lnb = (const float*)d_in[17];
    const float* qkvw = (const float*)d_in[18];
    const float* qkvb = (const float*)d_in[19];
    const float* projw = (const float*)d_in[20];
    const float* projb = (const float*)d_in[21];
    float* outp = (float*)d_out;

    char* ws = (char*)d_ws;
    bf16* p0pad = (bf16*)(ws + 0);              // [12][128][258][128] = 101,449,728
    bf16* wr3d2 = (bf16*)(ws + 101449728ull);
    bf16* wr3d3 = (bf16*)(ws + 103219200ull);
    bf16* wr2d2 = (bf16*)(ws + 110297088ull);
    bf16* wr2d3 = (bf16*)(ws + 110886912ull);
    bf16* qkvt  = (bf16*)(ws + 113246208ull);
    bf16* projt = (bf16*)(ws + 117964800ull);
    bf16* latbf = (bf16*)(ws + 119537664ull);
    bf16* w13d  = (bf16*)(ws + 120061952ull);
    bf16* w12d  = (bf16*)(ws + 120102912ull);
    bf16* p1pad = (bf16*)(ws + 120127488ull);   // [6][64][130][256]
    bf16* s0pad = (bf16*)(ws + 145686528ull);   // [128][258][128]
    bf16* s1pad = (bf16*)(ws + 154140672ull);   // [64][130][256]
    bf16* featsT= (bf16*)(ws + 158400512ull);   // [8192][512]
    float* lat  = (float*)(ws + 166789120ull);  // [8192][512] fp32 -> 183,566,336 total
    bf16* A3 = (bf16*)(ws + 120127488ull);      // im2col 3d half (over p1..lat)
    bf16* A2 = (bf16*)(ws + 158400512ull);      // im2col 2d (over featsT)
    bf16* ybf    = (bf16*)(ws + 0);             //  8,388,608
    bf16* qkvbuf = (bf16*)(ws + 8388608ull);    // 25,165,824
    bf16* attno  = (bf16*)(ws + 33554432ull);   //  8,388,608
    bf16* vT     = (bf16*)(ws + 41943040ull);   //  8,388,608 [512][8192]

    // 1) weight prep
    wprep_k<<<3456, 256, 0, stream>>>(pw1, wr3d2, 256, 128, 27);
    wprep_k<<<13824, 256, 0, stream>>>(pw2, wr3d3, 512, 256, 27);
    wprep_k<<<1152, 256, 0, stream>>>(sw1, wr2d2, 256, 128, 9);
    wprep_k<<<4608, 256, 0, stream>>>(sw2, wr2d3, 512, 256, 9);
    for (int r = 0; r < 3; r++) {
        tprep_k<<<3072, 256, 0, stream>>>(qkvw + (size_t)r * 786432, qkvt + (size_t)r * 786432, 512, 1536);
        tprep_k<<<1024, 256, 0, stream>>>(projw + (size_t)r * 262144, projt + (size_t)r * 262144, 512, 512);
    }
    cast_k<<<1024, 256, 0, stream>>>(latw, latbf, 262144);
    w1prep_k<<<80, 256, 0, stream>>>(pw0, w13d, 128, 5, 27, 160);
    w1prep_k<<<48, 256, 0, stream>>>(sw0, w12d, 128, 8, 9, 96);

    // 2) zero p0pad (halo)
    fill0_k<<<24768, 256, 0, stream>>>((uint4*)p0pad, 6340608);

    // 3) conv3d#1 via im2col + MFMA GEMM, two od-halves
    im2col3d_k<<<15360, 256, 0, stream>>>(x3d, A3, 0);
    conv1_gemm<<<1536, 256, 0, stream>>>(A3, w13d, pb0, p0pad, 196608, 160, 0);
    im2col3d_k<<<15360, 256, 0, stream>>>(x3d, A3, 6);
    conv1_gemm<<<1536, 256, 0, stream>>>(A3, w13d, pb0, p0pad, 196608, 160, 768);

    // 4) zero p1pad+s0pad+s1pad (halos); then conv2d#1
    fill0_k<<<9344, 256, 0, stream>>>((uint4*)p1pad, 2392064);
    im2col2d_k<<<1536, 256, 0, stream>>>(x2d, A2);
    conv1_gemm<<<256, 256, 0, stream>>>(A2, w12d, sb0, s0pad, 32768, 96, 0);

    // 5) conv chains (#2/#3) — 1D grids, XCD-swizzled inside
    conv_mfma2<128, 1><<<dim3(128), 256, 0, stream>>>(s0pad, wr2d2, sb1, s1pad, 1, 128, 258, 128, 64, 256, 130, 1, 2);
    conv_mfma2<64, 1><<<dim3(128), 256, 0, stream>>>(s1pad, wr2d3, sb2, featsT + (size_t)6144 * 512, 1, 64, 130, 256, 32, 512, 64, 0, 4);
    conv_mfma2<128, 3><<<dim3(768), 256, 0, stream>>>(p0pad, wr3d2, pb1, p1pad, 12, 128, 258, 128, 64, 256, 130, 1, 2);
    conv_mfma2<64, 3><<<dim3(384), 256, 0, stream>>>(p1pad, wr3d3, pb2, featsT, 6, 64, 130, 256, 32, 512, 64, 0, 4);

    // 6) lateral 1x1 conv
    gemm_bt<float, 0, 0><<<dim3(4, 64), 256, 0, stream>>>(featsT, latbf, latb, lat, nullptr, nullptr, 8192, 512, 512);

    // 7) 3 attention rounds
    for (int r = 0; r < 3; r++) {
        ln_k<<<2048, 256, 0, stream>>>(lat, lng + r * 512, lnb + r * 512, ybf);
        gemm_bt<bf16, 0, 1><<<dim3(12, 64), 256, 0, stream>>>(ybf, qkvt + (size_t)r * 786432, qkvb + r * 1536,
                                                              qkvbuf, nullptr, vT, 8192, 1536, 512);
        natt_mfma<<<dim3(128, 8), 256, 0, stream>>>(qkvbuf, vT, attno);
        gemm_bt<float, 1, 0><<<dim3(4, 64), 256, 0, stream>>>(attno, projt + (size_t)r * 262144, projb + r * 512,
                                                              lat, lat, nullptr, 8192, 512, 512);
    }

    // 8) transpose to planar output [512][4][32][64]
    tout_k<<<dim3(128, 8), 256, 0, stream>>>(lat, outp);
}

// Round 5
// 1213.055 us; speedup vs baseline: 1.2651x; 1.1466x over previous
//
#include <hip/hip_runtime.h>
#include <hip/hip_bf16.h>
#include <math.h>

typedef __hip_bfloat16 bf16;
typedef __attribute__((ext_vector_type(8))) short s8v;
typedef __attribute__((ext_vector_type(4))) float f4v;

__device__ __forceinline__ float ldf(const float* p) { return *p; }
__device__ __forceinline__ float ldf(const bf16* p) { return __bfloat162float(*p); }
__device__ __forceinline__ void stf(float* p, float v) { *p = v; }
__device__ __forceinline__ void stf(bf16* p, float v) { *p = __float2bfloat16(v); }

__device__ __forceinline__ float gelu_tanh(float x) {
    float x3 = x * x * x;
    return 0.5f * x * (1.f + tanhf(0.7978845608028654f * (x + 0.044715f * x3)));
}
__device__ __forceinline__ unsigned short bfbits(float x) {
    bf16 t = __float2bfloat16(x);
    return *(unsigned short*)&t;
}

// async global->LDS 16B: LDS dest must be wave-uniform base (+ lane*16 by HW);
// global src is per-lane.
__device__ __forceinline__ void gload16(const bf16* g, bf16* l)
{
    __builtin_amdgcn_global_load_lds(
        (const __attribute__((address_space(1))) unsigned int*)g,
        (__attribute__((address_space(3))) unsigned int*)l,
        16, 0, 0);
}

// ---------------- zero fill (16B granules) ----------------
__global__ __launch_bounds__(256) void fill0_k(uint4* __restrict__ p, int n16)
{
    int i = blockIdx.x * 256 + threadIdx.x;
    if (i < n16) p[i] = uint4{0u, 0u, 0u, 0u};
}

// ---------------- weight reorder: fp32 [OC][IC][T] -> bf16 [T][OC][IC] ----------------
__global__ __launch_bounds__(256) void wprep_k(const float* __restrict__ w, bf16* __restrict__ wr,
                                               int OC, int IC, int T)
{
    int i = blockIdx.x * 256 + threadIdx.x;
    if (i >= OC * IC * T) return;
    int t = i % T; int rem = i / T; int ic = rem % IC; int oc = rem / IC;
    wr[((size_t)t * OC + oc) * IC + ic] = __float2bfloat16(w[i]);
}

// ---------------- conv#1 weight prep: fp32 [OC][nic][ntap] -> bf16 [OC][Kp], k=tap*nic+ic ----------------
__global__ __launch_bounds__(256) void w1prep_k(const float* __restrict__ w, bf16* __restrict__ o,
                                                int OC, int nic, int ntap, int Kp)
{
    int i = blockIdx.x * 256 + threadIdx.x;
    if (i >= OC * Kp) return;
    int oc = i / Kp, k = i - oc * Kp;
    float v = 0.f;
    if (k < nic * ntap) {
        int tap = k / nic, ic = k - tap * nic;
        v = w[((size_t)oc * nic + ic) * ntap + tap];
    }
    o[i] = __float2bfloat16(v);
}

// ---------------- transpose cast: fp32 [K][N] -> bf16 [N][K] ----------------
__global__ __launch_bounds__(256) void tprep_k(const float* __restrict__ w, bf16* __restrict__ wt,
                                               int K, int N)
{
    int i = blockIdx.x * 256 + threadIdx.x;
    if (i >= K * N) return;
    int n = i % N, k = i / N;
    wt[(size_t)n * K + k] = __float2bfloat16(w[i]);
}

// ---------------- plain cast fp32 -> bf16 ----------------
__global__ __launch_bounds__(256) void cast_k(const float* __restrict__ w, bf16* __restrict__ o, int n)
{
    int i = blockIdx.x * 256 + threadIdx.x;
    if (i < n) o[i] = __float2bfloat16(w[i]);
}

// ---------------- im2col for conv3d#1: x3d fp32 [5][24][256][512] -> A bf16 [196608][160] ----------------
__global__ __launch_bounds__(256) void im2col3d_k(const float* __restrict__ x, bf16* __restrict__ A, int od0)
{
    int gid = blockIdx.x * 256 + threadIdx.x;  // 196608*20
    int m = gid / 20, kg = gid - 20 * (gid / 20);
    int ow = m & 255, rowid = m >> 8;
    int oh = rowid & 127, od = od0 + (rowid >> 7);
    int iz0 = 2 * od - 1, iy0 = 2 * oh - 1, ix0 = 2 * ow - 1;
    union { uint4 u; unsigned short h[8]; } pk;
#pragma unroll
    for (int j = 0; j < 8; j++) {
        int k = kg * 8 + j;
        float v = 0.f;
        if (k < 135) {
            int tap = k / 5, ic = k - tap * 5;
            int kz = tap / 9, r = tap - kz * 9;
            int ky = r / 3, kx = r - ky * 3;
            int iz = iz0 + kz, iy = iy0 + ky, ix = ix0 + kx;
            if ((unsigned)iz < 24u && (unsigned)iy < 256u && (unsigned)ix < 512u)
                v = x[(((size_t)ic * 24 + iz) * 256 + iy) * 512 + ix];
        }
        pk.h[j] = bfbits(v);
    }
    *(uint4*)&A[(size_t)m * 160 + kg * 8] = pk.u;
}

// ---------------- im2col for conv2d#1: x2d fp32 [8][256][512] -> A bf16 [32768][96] ----------------
__global__ __launch_bounds__(256) void im2col2d_k(const float* __restrict__ x, bf16* __restrict__ A)
{
    int gid = blockIdx.x * 256 + threadIdx.x;  // 32768*12
    int m = gid / 12, kg = gid - 12 * (gid / 12);
    int ow = m & 255, oh = m >> 8;
    int iy0 = 2 * oh - 1, ix0 = 2 * ow - 1;
    union { uint4 u; unsigned short h[8]; } pk;
#pragma unroll
    for (int j = 0; j < 8; j++) {
        int k = kg * 8 + j;
        float v = 0.f;
        if (k < 72) {
            int tap = k >> 3, ic = k & 7;
            int ky = tap / 3, kx = tap - ky * 3;
            int iy = iy0 + ky, ix = ix0 + kx;
            if ((unsigned)iy < 256u && (unsigned)ix < 512u)
                v = x[((size_t)ic * 256 + iy) * 512 + ix];
        }
        pk.h[j] = bfbits(v);
    }
    *(uint4*)&A[(size_t)m * 96 + kg * 8] = pk.u;
}

// ---------------- conv#1 GEMM: C = A[M][Kp] x W[128][Kp]^T, +bias, GELU, padded NHWC store ----------------
__global__ __launch_bounds__(256) void conv1_gemm(
    const bf16* __restrict__ A, const bf16* __restrict__ W, const float* __restrict__ bias,
    bf16* __restrict__ out, int M, int Kp, int rowOff)
{
    __shared__ __align__(16) bf16 As[128 * 32];
    __shared__ __align__(16) bf16 Bs[128 * 32];
    int tid = threadIdx.x;
    int m0 = blockIdx.x * 128;
    int wave = tid >> 6, lane = tid & 63;
    int wb = tid & 192;
    int wm = (wave >> 1) * 64, wn = (wave & 1) * 64;
    int lm = lane & 15, lq = lane >> 4;
    f4v acc[4][4];
#pragma unroll
    for (int i = 0; i < 4; i++)
#pragma unroll
        for (int j = 0; j < 4; j++) acc[i][j] = f4v{0.f, 0.f, 0.f, 0.f};
    for (int k0 = 0; k0 < Kp; k0 += 32) {
        __syncthreads();
#pragma unroll
        for (int c = 0; c < 2; c++) {
            int i = c * 256 + tid;
            int row = i >> 2, kq = i & 3;
            gload16(&A[(size_t)(m0 + row) * Kp + k0 + kq * 8], &As[(c * 256 + wb) * 8]);
            gload16(&W[(size_t)row * Kp + k0 + kq * 8], &Bs[(c * 256 + wb) * 8]);
        }
        __syncthreads();
        s8v af[4], bfr[4];
#pragma unroll
        for (int mi = 0; mi < 4; mi++) af[mi] = *(const s8v*)&As[(wm + mi * 16 + lm) * 32 + lq * 8];
#pragma unroll
        for (int ni = 0; ni < 4; ni++) bfr[ni] = *(const s8v*)&Bs[(wn + ni * 16 + lm) * 32 + lq * 8];
#pragma unroll
        for (int mi = 0; mi < 4; mi++)
#pragma unroll
            for (int ni = 0; ni < 4; ni++)
                acc[mi][ni] = __builtin_amdgcn_mfma_f32_16x16x32_bf16(af[mi], bfr[ni], acc[mi][ni], 0, 0, 0);
    }
#pragma unroll
    for (int mi = 0; mi < 4; mi++)
#pragma unroll
        for (int ni = 0; ni < 4; ni++)
#pragma unroll
            for (int r = 0; r < 4; r++) {
                int m = m0 + wm + mi * 16 + lq * 4 + r;
                int n = wn + ni * 16 + lm;
                int row = rowOff + (m >> 8), x = m & 255;
                float v = acc[mi][ni][r] + bias[n];
                out[((size_t)row * 258 + 1 + x) * 128 + n] = __float2bfloat16(gelu_tanh(v));
            }
}

// ================= MFMA tap-GEMM conv (#2/#3): 3 kx-taps per barrier =================
// 1D grid with XCD-aware swizzle.
template <int BM, int KD>
__global__ __launch_bounds__(256) void conv_mfma2(
    const bf16* __restrict__ in, const bf16* __restrict__ wr, const float* __restrict__ bias,
    bf16* __restrict__ out, int ID, int IH, int IWp, int IC,
    int OH, int OC, int OWS, int outPad, int nx)
{
    constexpr int NI = (BM == 128) ? 4 : 2;
    __shared__ __align__(16) bf16 As[3 * BM * 32];
    __shared__ __align__(16) bf16 Bs[3 * 128 * 32];
    int tid = threadIdx.x;
    int nwg = gridDim.x;                    // always a multiple of 8
    int bl = blockIdx.x;
    int swz = (bl & 7) * (nwg >> 3) + (bl >> 3);
    int n0 = (swz % nx) * 128;
    int rowid = swz / nx;
    int od = rowid / OH, oh = rowid % OH;
    int wave = tid >> 6, lane = tid & 63;
    int wb = tid & 192;                     // wave*64
    int wm = (BM == 128) ? (wave >> 1) * 64 : 0;
    int wn = (BM == 128) ? (wave & 1) * 64 : wave * 32;
    int lm = lane & 15, lq = lane >> 4;
    f4v acc[4][NI];
#pragma unroll
    for (int i = 0; i < 4; i++)
#pragma unroll
        for (int j = 0; j < NI; j++) acc[i][j] = f4v{0.f, 0.f, 0.f, 0.f};

    for (int kz = 0; kz < KD; kz++) {
        int iz = (KD == 3) ? (2 * od + kz - 1) : 0;
        if ((unsigned)iz >= (unsigned)ID) continue;
        for (int ky = 0; ky < 3; ky++) {
            int iy = 2 * oh + ky - 1;
            if ((unsigned)iy >= (unsigned)IH) continue;
            const bf16* inrow = in + ((size_t)iz * IH + iy) * IWp * IC;
            const bf16* wbase = wr + (size_t)((kz * 3 + ky) * 3) * OC * IC;
            for (int kb = 0; kb < IC; kb += 32) {
                __syncthreads();
#pragma unroll
                for (int c = 0; c < (3 * BM) / 64; c++) {
                    int i = c * 256 + tid;
                    int kx = i / (BM * 4);
                    int r = i - kx * (BM * 4);
                    int m = r >> 2, sub = r & 3;
                    gload16(&inrow[(size_t)(2 * m + kx) * IC + kb + sub * 8],
                            &As[(c * 256 + wb) * 8]);
                }
#pragma unroll
                for (int c = 0; c < 6; c++) {
                    int i = c * 256 + tid;
                    int t3 = i >> 9, r = i & 511, n = r >> 2, sub = r & 3;
                    gload16(&wbase[((size_t)t3 * OC + n0 + n) * IC + kb + sub * 8],
                            &Bs[(c * 256 + wb) * 8]);
                }
                __syncthreads();
#pragma unroll
                for (int kx = 0; kx < 3; kx++) {
                    s8v af[4], bfr[NI];
#pragma unroll
                    for (int mi = 0; mi < 4; mi++)
                        af[mi] = *(const s8v*)&As[(kx * BM + wm + mi * 16 + lm) * 32 + lq * 8];
#pragma unroll
                    for (int ni = 0; ni < NI; ni++)
                        bfr[ni] = *(const s8v*)&Bs[(kx * 128 + wn + ni * 16 + lm) * 32 + lq * 8];
#pragma unroll
                    for (int mi = 0; mi < 4; mi++)
#pragma unroll
                        for (int ni = 0; ni < NI; ni++)
                            acc[mi][ni] = __builtin_amdgcn_mfma_f32_16x16x32_bf16(af[mi], bfr[ni], acc[mi][ni], 0, 0, 0);
                }
            }
        }
    }
    size_t orowbase = ((size_t)rowid * OWS + outPad) * OC;
#pragma unroll
    for (int mi = 0; mi < 4; mi++)
#pragma unroll
        for (int ni = 0; ni < NI; ni++)
#pragma unroll
            for (int r = 0; r < 4; r++) {
                int m = wm + mi * 16 + lq * 4 + r;
                int n = n0 + wn + ni * 16 + lm;
                float v = acc[mi][ni][r] + bias[n];
                out[orowbase + (size_t)m * OC + n] = __float2bfloat16(gelu_tanh(v));
            }
}

// ================= MFMA GEMM: C[M,N] = A[M,K] * Bt[N,K]^T + bias (+res) (+vT side-write) ==========
template <typename OutT, int RES, int VT>
__global__ __launch_bounds__(256) void gemm_bt(
    const bf16* __restrict__ A, const bf16* __restrict__ Bt, const float* __restrict__ bias,
    OutT* __restrict__ C, const float* __restrict__ res, bf16* __restrict__ vt,
    int M, int N, int K)
{
    __shared__ __align__(16) bf16 As[128 * 32];
    __shared__ __align__(16) bf16 Bs[128 * 32];
    int tid = threadIdx.x;
    int n0 = blockIdx.x * 128, m0 = blockIdx.y * 128;
    int wave = tid >> 6, lane = tid & 63;
    int wb = tid & 192;
    int wm = (wave >> 1) * 64, wn = (wave & 1) * 64;
    int lm = lane & 15, lq = lane >> 4;
    f4v acc[4][4];
#pragma unroll
    for (int i = 0; i < 4; i++)
#pragma unroll
        for (int j = 0; j < 4; j++) acc[i][j] = f4v{0.f, 0.f, 0.f, 0.f};
    for (int k0 = 0; k0 < K; k0 += 32) {
        __syncthreads();
#pragma unroll
        for (int c = 0; c < 2; c++) {
            int i = c * 256 + tid;
            int row = i >> 2, kq = i & 3;
            gload16(&A[(size_t)(m0 + row) * K + k0 + kq * 8], &As[(c * 256 + wb) * 8]);
            gload16(&Bt[(size_t)(n0 + row) * K + k0 + kq * 8], &Bs[(c * 256 + wb) * 8]);
        }
        __syncthreads();
        s8v af[4], bfr[4];
#pragma unroll
        for (int mi = 0; mi < 4; mi++) af[mi] = *(const s8v*)&As[(wm + mi * 16 + lm) * 32 + lq * 8];
#pragma unroll
        for (int ni = 0; ni < 4; ni++) bfr[ni] = *(const s8v*)&Bs[(wn + ni * 16 + lm) * 32 + lq * 8];
#pragma unroll
        for (int mi = 0; mi < 4; mi++)
#pragma unroll
            for (int ni = 0; ni < 4; ni++)
                acc[mi][ni] = __builtin_amdgcn_mfma_f32_16x16x32_bf16(af[mi], bfr[ni], acc[mi][ni], 0, 0, 0);
    }
#pragma unroll
    for (int mi = 0; mi < 4; mi++)
#pragma unroll
        for (int ni = 0; ni < 4; ni++) {
            int n = n0 + wn + ni * 16 + lm;
            int mbase = m0 + wm + mi * 16 + lq * 4;
            float b = bias[n];
            if (VT && n >= 1024) {
                ushort4 pk;
                pk.x = bfbits(acc[mi][ni][0] + b);
                pk.y = bfbits(acc[mi][ni][1] + b);
                pk.z = bfbits(acc[mi][ni][2] + b);
                pk.w = bfbits(acc[mi][ni][3] + b);
                *(ushort4*)&vt[(size_t)(n - 1024) * 8192 + mbase] = pk;
            }
#pragma unroll
            for (int r = 0; r < 4; r++) {
                int m = mbase + r;
                float v = acc[mi][ni][r] + b;
                if (RES) v += res[(size_t)m * N + n];
                stf(&C[(size_t)m * N + n], v);
            }
        }
}

// ---------------- LayerNorm: lat fp32 [P,512] -> y bf16 [P,512]; one wave per token ----------------
__global__ __launch_bounds__(256) void ln_k(
    const float* __restrict__ lat, const float* __restrict__ g, const float* __restrict__ b,
    bf16* __restrict__ y)
{
    int tok = blockIdx.x * 4 + (threadIdx.x >> 6);
    int lane = threadIdx.x & 63;
    const float4* row = (const float4*)&lat[(size_t)tok * 512 + lane * 8];
    float4 a = row[0], c = row[1];
    float s = a.x + a.y + a.z + a.w + c.x + c.y + c.z + c.w;
    float ss = a.x * a.x + a.y * a.y + a.z * a.z + a.w * a.w
             + c.x * c.x + c.y * c.y + c.z * c.z + c.w * c.w;
#pragma unroll
    for (int off = 32; off; off >>= 1) {
        s += __shfl_xor(s, off);
        ss += __shfl_xor(ss, off);
    }
    float mu = s * (1.f / 512.f);
    float var = ss * (1.f / 512.f) - mu * mu;
    float rstd = rsqrtf(var + 1e-5f);
    const float4* gp = (const float4*)&g[lane * 8];
    const float4* bp = (const float4*)&b[lane * 8];
    float4 g0 = gp[0], g1 = gp[1], b0 = bp[0], b1 = bp[1];
    union { uint4 u; unsigned short h[8]; } pk;
    pk.h[0] = bfbits((a.x - mu) * rstd * g0.x + b0.x);
    pk.h[1] = bfbits((a.y - mu) * rstd * g0.y + b0.y);
    pk.h[2] = bfbits((a.z - mu) * rstd * g0.z + b0.z);
    pk.h[3] = bfbits((a.w - mu) * rstd * g0.w + b0.w);
    pk.h[4] = bfbits((c.x - mu) * rstd * g1.x + b1.x);
    pk.h[5] = bfbits((c.y - mu) * rstd * g1.y + b1.y);
    pk.h[6] = bfbits((c.z - mu) * rstd * g1.z + b1.z);
    pk.h[7] = bfbits((c.w - mu) * rstd * g1.w + b1.w);
    *(uint4*)&y[(size_t)tok * 512 + lane * 8] = pk.u;
}

// ================= MFMA flash-style neighborhood attention =================
// grid (128 rows, 8 heads); block 512 = 8 waves. Wave = (olane 0..3, rhalf 0..1):
// olane picks the (dz,dy) offset lane (idx = olane + 4t, as before); rhalf owns row
// blocks mi = {rhalf*2, rhalf*2+1}. Halves the per-wave accumulator state (Oa 32 regs,
// mr/lr 16) to get VGPR <= 128 -> 4 waves/SIMD residency (the 128-reg occupancy cliff
// was the invariant limiter across r1-r4: all landed in the (128,256] = 2-wave bucket).
// Math is bitwise identical to r4: same row ownership, same MFMA order, band-select
// softmax, defer-max, XOR-swizzled P tiles, heavy-block-first remap.
__global__ __launch_bounds__(512) void natt_mfma(
    const bf16* __restrict__ qkv, const bf16* __restrict__ vT, bf16* __restrict__ o)
{
    __shared__ __align__(16) char smem[40960];
    // layout: [0,8192) swizzled Q rows (128B each); [8192,40960) 4x per-olane P tiles.
    // epilogue aliases: mlb over dead qs, obuf over dead pb[0..1].
    float* mlb = (float*)smem;                 // [4 olanes][2][64] fp32 (epilogue)
    float* obuf = (float*)(smem + 8192);       // [64][65] fp32 (epilogue)
    int tid = threadIdx.x;
    // work-ordered remap: interior (heavy) blocks start first; corners drain last.
    int bx = blockIdx.x;
    int rd = bx >> 5, rh = bx & 31;
    int d = (rd == 0) ? 1 : (rd == 1) ? 2 : (rd == 2) ? 0 : 3;
    int h = (rh < 26) ? (rh + 3) : (rh == 26) ? 2 : (rh == 27) ? 29
          : (rh == 28) ? 1 : (rh == 29) ? 30 : (rh == 30) ? 0 : 31;
    int rowid = d * 32 + h;
    int head = blockIdx.y;
    int rowbase = rowid * 64;
    int hoff = head * 64;
    int wave = tid >> 6, lane = tid & 63;
    int olane = wave & 3, rhalf = wave >> 2;
    int lm = lane & 15, lq = lane >> 4;
    char* qsb = smem;
    bf16* pb = (bf16*)(smem + 8192 + olane * 8192);  // per-olane P [64][64], XOR-swizzled

    // stage Q tile [64 rows][64 dims], rows XOR-swizzled in 16B granules
    {
        int row = tid >> 3, sub = tid & 7;
        *(uint4*)(qsb + row * 128 + ((sub * 16) ^ ((row & 7) << 4))) =
            *(const uint4*)&qkv[(size_t)(rowbase + row) * 1536 + hoff + sub * 8];
    }
    // pre-zero all 4 P tiles (32 KB); cols never claimed by a lane stay 0 forever
    {
        uint4 z{0u, 0u, 0u, 0u};
        uint4* zp = (uint4*)(smem + 8192);
        zp[tid] = z; zp[tid + 512] = z; zp[tid + 1024] = z; zp[tid + 1536] = z;
    }
    __syncthreads();

    f4v Oa[2][4];
#pragma unroll
    for (int i = 0; i < 2; i++)
#pragma unroll
        for (int j = 0; j < 4; j++) Oa[i][j] = f4v{0.f, 0.f, 0.f, 0.f};
    float mr[2][4], lr[2][4];
#pragma unroll
    for (int i = 0; i < 2; i++)
#pragma unroll
        for (int j = 0; j < 4; j++) { mr[i][j] = -1e30f; lr[i][j] = 0.f; }

    for (int idx = olane; idx < 35; idx += 4) {
        int dz = idx / 7 - 2, dy = idx % 7 - 3;
        int zz = d + dz, yy = h + dy;
        if ((unsigned)zz >= 4u || (unsigned)yy >= 32u) continue;
        int kbase = (zz * 32 + yy) * 64;
        // K loads for this offset
        s8v kf[4][2];
#pragma unroll
        for (int ni = 0; ni < 4; ni++)
#pragma unroll
            for (int c = 0; c < 2; c++)
                kf[ni][c] = *(const s8v*)&qkv[(size_t)(kbase + ni * 16 + lm) * 1536 + 512 + hoff + c * 32 + lq * 8];
        // per-mi QK^T + band-aware softmax (this wave owns mi = rhalf*2 + {0,1})
#pragma unroll
        for (int mj = 0; mj < 2; mj++) {
            int mi = rhalf * 2 + mj;
            int qrow = mi * 16 + lm;
            s8v qc0 = *(const s8v*)(qsb + qrow * 128 + ((lq * 16) ^ ((qrow & 7) << 4)));
            s8v qc1 = *(const s8v*)(qsb + qrow * 128 + ((64 + lq * 16) ^ ((qrow & 7) << 4)));
            f4v s[4];
#pragma unroll
            for (int ni = 0; ni < 4; ni++) s[ni] = f4v{0.f, 0.f, 0.f, 0.f};
            __builtin_amdgcn_s_setprio(1);
#pragma unroll
            for (int ni = 0; ni < 4; ni++)
                s[ni] = __builtin_amdgcn_mfma_f32_16x16x32_bf16(qc0, kf[ni][0], s[ni], 0, 0, 0);
#pragma unroll
            for (int ni = 0; ni < 4; ni++)
                s[ni] = __builtin_amdgcn_mfma_f32_16x16x32_bf16(qc1, kf[ni][1], s[ni], 0, 0, 0);
            __builtin_amdgcn_s_setprio(0);
#pragma unroll
            for (int r = 0; r < 4; r++) {
                int w0 = mi * 16 + lq * 4 + r;
                float s0v = s[0][r], s1v = s[1][r], s2v = s[2][r], s3v = s[3][r];
                // unique candidate ni for this lane (band 7 < 16 apart)
                int t = w0 + 8 - lm;
                int niq = (t < 0) ? 0 : (t >> 4);
                niq = (niq > 3) ? 3 : niq;
                float vlo = (niq & 1) ? s1v : s0v;
                float vhi = (niq & 1) ? s3v : s2v;
                float v = (niq & 2) ? vhi : vlo;
                int col = (niq << 4) | lm;
                int dlt = col - w0;
                float vv = ((unsigned)(dlt + 3) <= 6u) ? v * 0.125f : -1e30f;
                float rm = vv;
#pragma unroll
                for (int off = 1; off <= 8; off <<= 1)
                    rm = fmaxf(rm, __shfl_xor(rm, off));
                float mo = mr[mj][r];
                float mn = mo;
                if (__any(rm > mo)) {      // rescale only when some row's max grew
                    mn = fmaxf(mo, rm);
                    float al = __expf(mo - mn);
                    mr[mj][r] = mn;
                    lr[mj][r] *= al;
#pragma unroll
                    for (int nd = 0; nd < 4; nd++)
                        Oa[mj][nd][r] *= al;
                }
                float p = __expf(vv - mn); // invalid lanes: exp(-1e30-mn) = 0
                float rs = p;
#pragma unroll
                for (int off = 1; off <= 8; off <<= 1)
                    rs += __shfl_xor(rs, off);
                lr[mj][r] += rs;
                pb[(w0 << 6) + (col ^ ((w0 & 7) << 3))] = __float2bfloat16(p);
            }
        }
        // V loads (issued before the LDS drain so they overlap it)
        s8v vf[4][2];
#pragma unroll
        for (int nd = 0; nd < 4; nd++)
#pragma unroll
            for (int c = 0; c < 2; c++)
                vf[nd][c] = *(const s8v*)&vT[(size_t)(hoff + nd * 16 + lm) * 8192 + kbase + c * 32 + lq * 8];
        __asm__ __volatile__("s_waitcnt lgkmcnt(0)" ::: "memory");
        __builtin_amdgcn_sched_barrier(0);
        // O += P V  (each wave reads only the P rows it wrote -> no cross-wave sync)
#pragma unroll
        for (int c = 0; c < 2; c++) {
            s8v pf[2];
#pragma unroll
            for (int mj = 0; mj < 2; mj++) {
                int mi = rhalf * 2 + mj;
                pf[mj] = *(const s8v*)&pb[((mi * 16 + lm) << 6) + ((c * 32 + lq * 8) ^ ((lm & 7) << 3))];
            }
            __builtin_amdgcn_s_setprio(1);
#pragma unroll
            for (int mj = 0; mj < 2; mj++)
#pragma unroll
                for (int nd = 0; nd < 4; nd++)
                    Oa[mj][nd] = __builtin_amdgcn_mfma_f32_16x16x32_bf16(pf[mj], vf[nd][c], Oa[mj][nd], 0, 0, 0);
            __builtin_amdgcn_s_setprio(0);
        }
    }
    // all waves done with qs (mlb alias) and pb reads (obuf alias) after this barrier
    __syncthreads();
    // publish per-(olane) m,l partials; the two rhalf waves fill disjoint rows
    if (lm == 0) {
#pragma unroll
        for (int mj = 0; mj < 2; mj++)
#pragma unroll
            for (int r = 0; r < 4; r++) {
                int row = (rhalf * 2 + mj) * 16 + lq * 4 + r;
                mlb[olane * 128 + row] = mr[mj][r];
                mlb[olane * 128 + 64 + row] = lr[mj][r];
            }
    }
    __syncthreads();
    // sequential cross-olane combine into obuf (rhalf pairs write disjoint rows)
    for (int wv = 0; wv < 4; wv++) {
        if (olane == wv) {
#pragma unroll
            for (int mj = 0; mj < 2; mj++)
#pragma unroll
                for (int r = 0; r < 4; r++) {
                    int row = (rhalf * 2 + mj) * 16 + lq * 4 + r;
                    float M = fmaxf(fmaxf(mlb[row], mlb[128 + row]),
                                    fmaxf(mlb[256 + row], mlb[384 + row]));
                    float sc = __expf(mr[mj][r] - M);
#pragma unroll
                    for (int nd = 0; nd < 4; nd++) {
                        int ci = row * 65 + nd * 16 + lm;
                        float add = Oa[mj][nd][r] * sc;
                        obuf[ci] = (wv == 0) ? add : (obuf[ci] + add);
                    }
                }
        }
        __syncthreads();
    }
    // final normalize + coalesced store (512 threads: 8 per row, 8 cols each)
    {
        int row = tid >> 3, cb = (tid & 7) * 8;
        float m0 = mlb[row], m1 = mlb[128 + row], m2 = mlb[256 + row], m3 = mlb[384 + row];
        float M = fmaxf(fmaxf(m0, m1), fmaxf(m2, m3));
        float L = mlb[64 + row] * __expf(m0 - M) + mlb[192 + row] * __expf(m1 - M)
                + mlb[320 + row] * __expf(m2 - M) + mlb[448 + row] * __expf(m3 - M);
        float inv = 1.f / L;
        union { uint4 u; unsigned short hs[8]; } pk;
#pragma unroll
        for (int j = 0; j < 8; j++)
            pk.hs[j] = bfbits(obuf[row * 65 + cb + j] * inv);
        *(uint4*)&o[(size_t)(rowbase + row) * 512 + hoff + cb] = pk.u;
    }
}

// ---------------- final transpose: lat [P,512] fp32 -> out planar [512,P] ----------------
__global__ __launch_bounds__(256) void tout_k(const float* __restrict__ lat, float* __restrict__ out)
{
    __shared__ float t[64][65];
    int p0 = blockIdx.x * 64, c0 = blockIdx.y * 64;
    for (int i = threadIdx.x; i < 4096; i += 256) {
        int r = i >> 6, cc = i & 63;
        t[r][cc] = lat[(size_t)(p0 + r) * 512 + c0 + cc];
    }
    __syncthreads();
    for (int i = threadIdx.x; i < 4096; i += 256) {
        int cc = i >> 6, r = i & 63;
        out[(size_t)(c0 + cc) * 8192 + p0 + r] = t[r][cc];
    }
}

extern "C" void kernel_launch(void* const* d_in, const int* in_sizes, int n_in,
                              void* d_out, int out_size, void* d_ws, size_t ws_size,
                              hipStream_t stream)
{
    const float* x2d = (const float*)d_in[0];
    const float* x3d = (const float*)d_in[1];
    const float* sw0 = (const float*)d_in[2];
    const float* sb0 = (const float*)d_in[3];
    const float* sw1 = (const float*)d_in[4];
    const float* sb1 = (const float*)d_in[5];
    const float* sw2 = (const float*)d_in[6];
    const float* sb2 = (const float*)d_in[7];
    const float* pw0 = (const float*)d_in[8];
    const float* pb0 = (const float*)d_in[9];
    const float* pw1 = (const float*)d_in[10];
    const float* pb1 = (const float*)d_in[11];
    const float* pw2 = (const float*)d_in[12];
    const float* pb2 = (const float*)d_in[13];
    const float* latw = (const float*)d_in[14];
    const float* latb = (const float*)d_in[15];
    const float* lng = (const float*)d_in[16];
    const float* lnb = (const float*)d_in[17];
    const float* qkvw = (const float*)d_in[18];
    const float* qkvb = (const float*)d_in[19];
    const float* projw = (const float*)d_in[20];
    const float* projb = (const float*)d_in[21];
    float* outp = (float*)d_out;

    char* ws = (char*)d_ws;
    bf16* p0pad = (bf16*)(ws + 0);              // [12][128][258][128] = 101,449,728
    bf16* wr3d2 = (bf16*)(ws + 101449728ull);
    bf16* wr3d3 = (bf16*)(ws + 103219200ull);
    bf16* wr2d2 = (bf16*)(ws + 110297088ull);
    bf16* wr2d3 = (bf16*)(ws + 110886912ull);
    bf16* qkvt  = (bf16*)(ws + 113246208ull);
    bf16* projt = (bf16*)(ws + 117964800ull);
    bf16* latbf = (bf16*)(ws + 119537664ull);
    bf16* w13d  = (bf16*)(ws + 120061952ull);
    bf16* w12d  = (bf16*)(ws + 120102912ull);
    bf16* p1pad = (bf16*)(ws + 120127488ull);   // [6][64][130][256]
    bf16* s0pad = (bf16*)(ws + 145686528ull);   // [128][258][128]
    bf16* s1pad = (bf16*)(ws + 154140672ull);   // [64][130][256]
    bf16* featsT= (bf16*)(ws + 158400512ull);   // [8192][512]
    float* lat  = (float*)(ws + 166789120ull);  // [8192][512] fp32 -> 183,566,336 total
    bf16* A3 = (bf16*)(ws + 120127488ull);      // im2col 3d half (over p1..lat)
    bf16* A2 = (bf16*)(ws + 158400512ull);      // im2col 2d (over featsT)
    bf16* ybf    = (bf16*)(ws + 0);             //  8,388,608
    bf16* qkvbuf = (bf16*)(ws + 8388608ull);    // 25,165,824
    bf16* attno  = (bf16*)(ws + 33554432ull);   //  8,388,608
    bf16* vT     = (bf16*)(ws + 41943040ull);   //  8,388,608 [512][8192]

    // 1) weight prep
    wprep_k<<<3456, 256, 0, stream>>>(pw1, wr3d2, 256, 128, 27);
    wprep_k<<<13824, 256, 0, stream>>>(pw2, wr3d3, 512, 256, 27);
    wprep_k<<<1152, 256, 0, stream>>>(sw1, wr2d2, 256, 128, 9);
    wprep_k<<<4608, 256, 0, stream>>>(sw2, wr2d3, 512, 256, 9);
    for (int r = 0; r < 3; r++) {
        tprep_k<<<3072, 256, 0, stream>>>(qkvw + (size_t)r * 786432, qkvt + (size_t)r * 786432, 512, 1536);
        tprep_k<<<1024, 256, 0, stream>>>(projw + (size_t)r * 262144, projt + (size_t)r * 262144, 512, 512);
    }
    cast_k<<<1024, 256, 0, stream>>>(latw, latbf, 262144);
    w1prep_k<<<80, 256, 0, stream>>>(pw0, w13d, 128, 5, 27, 160);
    w1prep_k<<<48, 256, 0, stream>>>(sw0, w12d, 128, 8, 9, 96);

    // 2) zero p0pad (halo)
    fill0_k<<<24768, 256, 0, stream>>>((uint4*)p0pad, 6340608);

    // 3) conv3d#1 via im2col + MFMA GEMM, two od-halves
    im2col3d_k<<<15360, 256, 0, stream>>>(x3d, A3, 0);
    conv1_gemm<<<1536, 256, 0, stream>>>(A3, w13d, pb0, p0pad, 196608, 160, 0);
    im2col3d_k<<<15360, 256, 0, stream>>>(x3d, A3, 6);
    conv1_gemm<<<1536, 256, 0, stream>>>(A3, w13d, pb0, p0pad, 196608, 160, 768);

    // 4) zero p1pad+s0pad+s1pad (halos); then conv2d#1
    fill0_k<<<9344, 256, 0, stream>>>((uint4*)p1pad, 2392064);
    im2col2d_k<<<1536, 256, 0, stream>>>(x2d, A2);
    conv1_gemm<<<256, 256, 0, stream>>>(A2, w12d, sb0, s0pad, 32768, 96, 0);

    // 5) conv chains (#2/#3) — 1D grids, XCD-swizzled inside
    conv_mfma2<128, 1><<<dim3(128), 256, 0, stream>>>(s0pad, wr2d2, sb1, s1pad, 1, 128, 258, 128, 64, 256, 130, 1, 2);
    conv_mfma2<64, 1><<<dim3(128), 256, 0, stream>>>(s1pad, wr2d3, sb2, featsT + (size_t)6144 * 512, 1, 64, 130, 256, 32, 512, 64, 0, 4);
    conv_mfma2<128, 3><<<dim3(768), 256, 0, stream>>>(p0pad, wr3d2, pb1, p1pad, 12, 128, 258, 128, 64, 256, 130, 1, 2);
    conv_mfma2<64, 3><<<dim3(384), 256, 0, stream>>>(p1pad, wr3d3, pb2, featsT, 6, 64, 130, 256, 32, 512, 64, 0, 4);

    // 6) lateral 1x1 conv
    gemm_bt<float, 0, 0><<<dim3(4, 64), 256, 0, stream>>>(featsT, latbf, latb, lat, nullptr, nullptr, 8192, 512, 512);

    // 7) 3 attention rounds
    for (int r = 0; r < 3; r++) {
        ln_k<<<2048, 256, 0, stream>>>(lat, lng + r * 512, lnb + r * 512, ybf);
        gemm_bt<bf16, 0, 1><<<dim3(12, 64), 256, 0, stream>>>(ybf, qkvt + (size_t)r * 786432, qkvb + r * 1536,
                                                              qkvbuf, nullptr, vT, 8192, 1536, 512);
        natt_mfma<<<dim3(128, 8), 512, 0, stream>>>(qkvbuf, vT, attno);
        gemm_bt<float, 1, 0><<<dim3(4, 64), 256, 0, stream>>>(attno, projt + (size_t)r * 262144, projb + r * 512,
                                                              lat, lat, nullptr, 8192, 512, 512);
    }

    // 8) transpose to planar output [512][4][32][64]
    tout_k<<<dim3(128, 8), 256, 0, stream>>>(lat, outp);
}